// Round 1
// baseline (2600.900 us; speedup 1.0000x reference)
//
#include <hip/hip_runtime.h>
#include <math.h>

#define L_SEQ  2048
#define BATCH  2
#define DMODEL 1024
#define DINNER 2048
#define DSTATE 16
#define DTRANK 64
#define NDBL   96
#define MROWS  (BATCH * L_SEQ)   // 4096

// ---------------------------------------------------------------------------
// Tiled fp32 GEMM: C[M,N](ldc) = epi(A[M,K](lda) @ B[N,K](ldb)^T)
// Both operands k-contiguous (weight stored (out,in) row-major => B^T form).
// 128x128 tile, KT=16, 256 threads, 8x8 microtile.
// EPI: 0 = plain, 1 = mul * sigmoid(acc + bias), 2 = softplus(acc + bias)
// Split-K via gridDim.z: block z handles K range [k0 + z*ksz, ...+ksz),
// writing to C + z*M*ldc.
// ---------------------------------------------------------------------------
template <int EPI>
__global__ __launch_bounds__(256) void gemm_tiled(
    const float* __restrict__ A, int lda,
    const float* __restrict__ Bw, int ldb,
    float* __restrict__ C, int ldc,
    int M, int N, int K,
    const float* __restrict__ bias,
    const float* __restrict__ mul,
    int k0, int ksz)
{
    __shared__ float As[16][132];
    __shared__ float Bs[16][132];
    const int tid = threadIdx.x;
    const int tx = tid & 15;
    const int ty = tid >> 4;
    const int row0 = blockIdx.y * 128;
    const int col0 = blockIdx.x * 128;
    const int kk0 = k0 + blockIdx.z * ksz;
    float* Cz = C + (size_t)blockIdx.z * (size_t)M * (size_t)ldc;

    float acc[8][8];
#pragma unroll
    for (int i = 0; i < 8; i++)
#pragma unroll
        for (int j = 0; j < 8; j++) acc[i][j] = 0.f;

    for (int kt = kk0; kt < kk0 + ksz; kt += 16) {
        // A tile: 128 rows x 16 k  (512 float4 loads by 256 threads x2)
#pragma unroll
        for (int rep = 0; rep < 2; rep++) {
            int idx = rep * 256 + tid;
            int i = idx >> 2;
            int kq = (idx & 3) * 4;
            const float4 v = *reinterpret_cast<const float4*>(
                &A[(size_t)(row0 + i) * lda + kt + kq]);
            As[kq + 0][i] = v.x; As[kq + 1][i] = v.y;
            As[kq + 2][i] = v.z; As[kq + 3][i] = v.w;
        }
        // B tile: 128 cols x 16 k (mask cols >= N with zeros)
#pragma unroll
        for (int rep = 0; rep < 2; rep++) {
            int idx = rep * 256 + tid;
            int j = idx >> 2;
            int kq = (idx & 3) * 4;
            float4 v = make_float4(0.f, 0.f, 0.f, 0.f);
            if (col0 + j < N)
                v = *reinterpret_cast<const float4*>(
                    &Bw[(size_t)(col0 + j) * ldb + kt + kq]);
            Bs[kq + 0][j] = v.x; Bs[kq + 1][j] = v.y;
            Bs[kq + 2][j] = v.z; Bs[kq + 3][j] = v.w;
        }
        __syncthreads();
#pragma unroll
        for (int k = 0; k < 16; k++) {
            float a[8], b[8];
#pragma unroll
            for (int i = 0; i < 8; i++) a[i] = As[k][ty * 8 + i];
#pragma unroll
            for (int j = 0; j < 8; j++) b[j] = Bs[k][tx * 8 + j];
#pragma unroll
            for (int i = 0; i < 8; i++)
#pragma unroll
                for (int j = 0; j < 8; j++)
                    acc[i][j] = fmaf(a[i], b[j], acc[i][j]);
        }
        __syncthreads();
    }

#pragma unroll
    for (int i = 0; i < 8; i++) {
        int r = row0 + ty * 8 + i;
#pragma unroll
        for (int j = 0; j < 8; j++) {
            int c = col0 + tx * 8 + j;
            if (c < N) {
                float v = acc[i][j];
                if (EPI == 1) {
                    v = 1.f / (1.f + __expf(-(v + bias[c])));
                    v *= mul[(size_t)r * N + c];
                } else if (EPI == 2) {
                    v += bias[c];
                    v = (v > 20.f) ? v : log1pf(__expf(v));
                }
                Cz[(size_t)r * ldc + c] = v;
            }
        }
    }
}

// Fixed-order split-K reduction (deterministic).
__global__ __launch_bounds__(256) void reduce_splitk(
    const float* __restrict__ part, float* __restrict__ out,
    int n, int nsplit, size_t stride)
{
    int i = blockIdx.x * 256 + threadIdx.x;
    if (i < n) {
        float s = 0.f;
        for (int j = 0; j < nsplit; j++) s += part[(size_t)j * stride + i];
        out[i] = s;
    }
}

// Depthwise causal conv (width 4) + bias + SiLU.
// x_in lives in xz columns [0, 2048), stride 4096.
__global__ __launch_bounds__(256) void conv_silu_kernel(
    const float* __restrict__ xz, const float* __restrict__ cw,
    const float* __restrict__ cb, float* __restrict__ xc)
{
    int gid = blockIdx.x * 256 + threadIdx.x;   // M * DINNER threads
    int e = gid & (DINNER - 1);
    int row = gid >> 11;                         // / DINNER
    int t = row & (L_SEQ - 1);
    float s = cb[e];
#pragma unroll
    for (int j = 0; j < 4; j++) {
        int tt = t - 3 + j;
        if (tt >= 0)
            s = fmaf(cw[e * 4 + j], xz[(size_t)(row - 3 + j) * 4096 + e], s);
    }
    xc[(size_t)row * 2048 + e] = s / (1.f + __expf(-s));
}

// Selective scan. 16 lanes per (b,e) channel (one state each).
// Fuses y = (scan_y + D*x_c) * silu(z); writes gated y over x_in cols of xz.
__global__ __launch_bounds__(256) void scan_kernel(
    const float* __restrict__ dt, const float* __restrict__ xc,
    const float* __restrict__ xdbl, float* __restrict__ xz,
    const float* __restrict__ A_log, const float* __restrict__ Dw)
{
    const int tid = threadIdx.x;
    const int s = tid & 15;
    const int g = blockIdx.x * 16 + (tid >> 4);   // global (b,e) group
    const int b = g >> 11;
    const int e = g & (DINNER - 1);
    const float a = -__expf(A_log[e * DSTATE + s]);
    const float dcoef = Dw[e];
    float h = 0.f;
    for (int t = 0; t < L_SEQ; t++) {
        const size_t base = (size_t)(b * L_SEQ + t);
        const float dtv = dt[base * 2048 + e];
        const float xv = xc[base * 2048 + e];
        const float Bv = xdbl[base * 96 + 64 + s];
        const float Cv = xdbl[base * 96 + 80 + s];
        h = __expf(dtv * a) * h + dtv * Bv * xv;
        float p = h * Cv;
        p += __shfl_xor(p, 1, 16);
        p += __shfl_xor(p, 2, 16);
        p += __shfl_xor(p, 4, 16);
        p += __shfl_xor(p, 8, 16);
        if (s == 0) {
            const float z = xz[base * 4096 + 2048 + e];
            xz[base * 4096 + e] = (p + dcoef * xv) * (z / (1.f + __expf(-z)));
        }
    }
}

extern "C" void kernel_launch(void* const* d_in, const int* in_sizes, int n_in,
                              void* d_out, int out_size, void* d_ws, size_t ws_size,
                              hipStream_t stream)
{
    const float* x_f    = (const float*)d_in[0];
    const float* x_h    = (const float*)d_in[1];
    const float* W_hf   = (const float*)d_in[2];
    const float* b_hf   = (const float*)d_in[3];
    const float* W_in   = (const float*)d_in[4];
    const float* conv_w = (const float*)d_in[5];
    const float* conv_b = (const float*)d_in[6];
    const float* W_x    = (const float*)d_in[7];
    const float* W_dt   = (const float*)d_in[8];
    const float* b_dt   = (const float*)d_in[9];
    const float* A_log  = (const float*)d_in[10];
    const float* Dw     = (const float*)d_in[11];
    const float* W_out  = (const float*)d_in[12];
    float* out = (float*)d_out;
    float* ws  = (float*)d_ws;

    // Workspace layout (floats). m region is reused for split-K partials+x_dbl
    // after m is consumed by GEMM-in.
    float* m    = ws;                    // 4,194,304 f
    float* xz   = ws + 4194304;          // 16,777,216 f  (x_in | z; later y | z)
    float* xc   = ws + 20971520;         // 8,388,608 f
    float* dt   = ws + 29360128;         // 8,388,608 f
    float* part = ws;                    // 8 * 4096 * 96 = 3,145,728 f (over m)
    float* xdbl = ws + 3145728;          // 393,216 f (still inside m region)
    // total: 37,748,736 floats = 151 MB

    const int M = MROWS;

    // 1. m = x_f * sigmoid(x_h @ W_hf^T + b_hf)
    gemm_tiled<1><<<dim3(DMODEL / 128, M / 128, 1), 256, 0, stream>>>(
        x_h, DMODEL, W_hf, DMODEL, m, DMODEL, M, DMODEL, DMODEL,
        b_hf, x_f, 0, DMODEL);

    // 2. xz = m @ W_in^T   (N = 4096)
    gemm_tiled<0><<<dim3(4096 / 128, M / 128, 1), 256, 0, stream>>>(
        m, DMODEL, W_in, DMODEL, xz, 4096, M, 4096, DMODEL,
        nullptr, nullptr, 0, DMODEL);

    // 3. x_c = silu(causal_conv4(x_in) + conv_b)
    conv_silu_kernel<<<(M * DINNER) / 256, 256, 0, stream>>>(xz, conv_w, conv_b, xc);

    // 4. x_dbl partials = x_c @ W_x^T  (N=96, split-K 8x256)
    gemm_tiled<0><<<dim3(1, M / 128, 8), 256, 0, stream>>>(
        xc, DINNER, W_x, DINNER, part, NDBL, M, NDBL, DINNER,
        nullptr, nullptr, 0, 256);
    reduce_splitk<<<(M * NDBL + 255) / 256, 256, 0, stream>>>(
        part, xdbl, M * NDBL, 8, (size_t)M * NDBL);

    // 5. dt = softplus(x_dbl[:, :64] @ W_dt^T + b_dt)
    gemm_tiled<2><<<dim3(DINNER / 128, M / 128, 1), 256, 0, stream>>>(
        xdbl, NDBL, W_dt, DTRANK, dt, DINNER, M, DINNER, DTRANK,
        b_dt, nullptr, 0, DTRANK);

    // 6. scan + skip + gating; writes y into xz cols [0,2048)
    scan_kernel<<<(BATCH * DINNER) / 16, 256, 0, stream>>>(
        dt, xc, xdbl, xz, A_log, Dw);

    // 7. out = y @ W_out^T
    gemm_tiled<0><<<dim3(DMODEL / 128, M / 128, 1), 256, 0, stream>>>(
        xz, 4096, W_out, DINNER, out, DMODEL, M, DMODEL, DINNER,
        nullptr, nullptr, 0, DINNER);
}

// Round 2
// 1555.797 us; speedup vs baseline: 1.6717x; 1.6717x over previous
//
#include <hip/hip_runtime.h>
#include <math.h>

#define L_SEQ  2048
#define BATCH  2
#define DMODEL 1024
#define DINNER 2048
#define DSTATE 16
#define DTRANK 64
#define NDBL   96
#define MROWS  (BATCH * L_SEQ)   // 4096
#define TTILE  32

// ---------------------------------------------------------------------------
// Tiled fp32 GEMM: C[M,N](ldc) = epi(A[M,K](lda) @ B[N,K](ldb)^T)
// Both operands k-contiguous (weight stored (out,in) row-major => B^T form).
// 128x128 tile, KT=16, 256 threads, 8x8 microtile.
// EPI: 0 = plain, 1 = mul * sigmoid(acc + bias), 2 = softplus(acc + bias)
// Split-K via gridDim.z: block z handles K range [k0 + z*ksz, ...+ksz),
// writing to C + z*M*ldc.
// ---------------------------------------------------------------------------
template <int EPI>
__global__ __launch_bounds__(256) void gemm_tiled(
    const float* __restrict__ A, int lda,
    const float* __restrict__ Bw, int ldb,
    float* __restrict__ C, int ldc,
    int M, int N, int K,
    const float* __restrict__ bias,
    const float* __restrict__ mul,
    int k0, int ksz)
{
    __shared__ float As[16][132];
    __shared__ float Bs[16][132];
    const int tid = threadIdx.x;
    const int tx = tid & 15;
    const int ty = tid >> 4;
    const int row0 = blockIdx.y * 128;
    const int col0 = blockIdx.x * 128;
    const int kk0 = k0 + blockIdx.z * ksz;
    float* Cz = C + (size_t)blockIdx.z * (size_t)M * (size_t)ldc;

    float acc[8][8];
#pragma unroll
    for (int i = 0; i < 8; i++)
#pragma unroll
        for (int j = 0; j < 8; j++) acc[i][j] = 0.f;

    for (int kt = kk0; kt < kk0 + ksz; kt += 16) {
        // A tile: 128 rows x 16 k  (512 float4 loads by 256 threads x2)
#pragma unroll
        for (int rep = 0; rep < 2; rep++) {
            int idx = rep * 256 + tid;
            int i = idx >> 2;
            int kq = (idx & 3) * 4;
            const float4 v = *reinterpret_cast<const float4*>(
                &A[(size_t)(row0 + i) * lda + kt + kq]);
            As[kq + 0][i] = v.x; As[kq + 1][i] = v.y;
            As[kq + 2][i] = v.z; As[kq + 3][i] = v.w;
        }
        // B tile: 128 cols x 16 k (mask cols >= N with zeros)
#pragma unroll
        for (int rep = 0; rep < 2; rep++) {
            int idx = rep * 256 + tid;
            int j = idx >> 2;
            int kq = (idx & 3) * 4;
            float4 v = make_float4(0.f, 0.f, 0.f, 0.f);
            if (col0 + j < N)
                v = *reinterpret_cast<const float4*>(
                    &Bw[(size_t)(col0 + j) * ldb + kt + kq]);
            Bs[kq + 0][j] = v.x; Bs[kq + 1][j] = v.y;
            Bs[kq + 2][j] = v.z; Bs[kq + 3][j] = v.w;
        }
        __syncthreads();
#pragma unroll
        for (int k = 0; k < 16; k++) {
            float a[8], b[8];
#pragma unroll
            for (int i = 0; i < 8; i++) a[i] = As[k][ty * 8 + i];
#pragma unroll
            for (int j = 0; j < 8; j++) b[j] = Bs[k][tx * 8 + j];
#pragma unroll
            for (int i = 0; i < 8; i++)
#pragma unroll
                for (int j = 0; j < 8; j++)
                    acc[i][j] = fmaf(a[i], b[j], acc[i][j]);
        }
        __syncthreads();
    }

#pragma unroll
    for (int i = 0; i < 8; i++) {
        int r = row0 + ty * 8 + i;
#pragma unroll
        for (int j = 0; j < 8; j++) {
            int c = col0 + tx * 8 + j;
            if (c < N) {
                float v = acc[i][j];
                if (EPI == 1) {
                    v = 1.f / (1.f + __expf(-(v + bias[c])));
                    v *= mul[(size_t)r * N + c];
                } else if (EPI == 2) {
                    v += bias[c];
                    v = (v > 20.f) ? v : log1pf(__expf(v));
                }
                Cz[(size_t)r * ldc + c] = v;
            }
        }
    }
}

// Fixed-order split-K reduction (deterministic).
__global__ __launch_bounds__(256) void reduce_splitk(
    const float* __restrict__ part, float* __restrict__ out,
    int n, int nsplit, size_t stride)
{
    int i = blockIdx.x * 256 + threadIdx.x;
    if (i < n) {
        float s = 0.f;
        for (int j = 0; j < nsplit; j++) s += part[(size_t)j * stride + i];
        out[i] = s;
    }
}

// Depthwise causal conv (width 4) + bias + SiLU.
// x_in lives in xz columns [0, 2048), stride 4096.
__global__ __launch_bounds__(256) void conv_silu_kernel(
    const float* __restrict__ xz, const float* __restrict__ cw,
    const float* __restrict__ cb, float* __restrict__ xc)
{
    int gid = blockIdx.x * 256 + threadIdx.x;   // M * DINNER threads
    int e = gid & (DINNER - 1);
    int row = gid >> 11;                         // / DINNER
    int t = row & (L_SEQ - 1);
    float s = cb[e];
#pragma unroll
    for (int j = 0; j < 4; j++) {
        int tt = t - 3 + j;
        if (tt >= 0)
            s = fmaf(cw[e * 4 + j], xz[(size_t)(row - 3 + j) * 4096 + e], s);
    }
    xc[(size_t)row * 2048 + e] = s / (1.f + __expf(-s));
}

// ---------------------------------------------------------------------------
// Selective scan, LDS-tiled + double-buffered (T14 async-stage split).
// Block = 256 threads = 16 channels x 16 states; grid = B*DINNER/16 = 256.
// Per TTILE=32 steps: issue next tile's global loads into registers, compute
// current tile from LDS (latency hidden under compute), commit regs to the
// alternate LDS buffer. y staged in LDS, flushed with coalesced float2.
// Fuses y = (scan_y + D*x_c) * silu(z); writes gated y over x_in cols of xz.
// ---------------------------------------------------------------------------
__global__ __launch_bounds__(256) void scan_kernel(
    const float* __restrict__ dt, const float* __restrict__ xc,
    const float* __restrict__ xdbl, float* __restrict__ xz,
    const float* __restrict__ A_log, const float* __restrict__ Dw)
{
    __shared__ float s_dt[2][TTILE][16];
    __shared__ float s_xc[2][TTILE][16];
    __shared__ float s_z [2][TTILE][16];
    __shared__ float s_B [2][TTILE][16];
    __shared__ float s_C [2][TTILE][16];
    __shared__ float s_y [TTILE][16];

    const int tid = threadIdx.x;
    const int b   = blockIdx.x >> 7;          // 128 blocks per batch
    const int e0  = (blockIdx.x & 127) << 4;  // 16 channels per block
    // cooperative-load mapping: li = t offset within tile, lj = elem pair
    const int li = tid >> 3;
    const int lj = (tid & 7) << 1;
    // compute mapping: c = channel in block, s = state
    const int c = tid >> 4;
    const int s = tid & 15;
    const float a = -__expf(A_log[(e0 + c) * DSTATE + s]);
    const float dcoef = Dw[e0 + c];
    const size_t rowbase = (size_t)b * L_SEQ;

    float2 r_dt, r_xc, r_z, r_B, r_C;

    // prologue: tile 0
    {
        const size_t row = rowbase + li;
        r_dt = *reinterpret_cast<const float2*>(&dt [row * 2048 + e0 + lj]);
        r_xc = *reinterpret_cast<const float2*>(&xc [row * 2048 + e0 + lj]);
        r_z  = *reinterpret_cast<const float2*>(&xz [row * 4096 + 2048 + e0 + lj]);
        r_B  = *reinterpret_cast<const float2*>(&xdbl[row * 96 + 64 + lj]);
        r_C  = *reinterpret_cast<const float2*>(&xdbl[row * 96 + 80 + lj]);
        *reinterpret_cast<float2*>(&s_dt[0][li][lj]) = r_dt;
        *reinterpret_cast<float2*>(&s_xc[0][li][lj]) = r_xc;
        *reinterpret_cast<float2*>(&s_z [0][li][lj]) = r_z;
        *reinterpret_cast<float2*>(&s_B [0][li][lj]) = r_B;
        *reinterpret_cast<float2*>(&s_C [0][li][lj]) = r_C;
    }
    __syncthreads();

    float h = 0.f;
    const int NT = L_SEQ / TTILE;   // 64
    for (int k = 0; k < NT; k++) {
        const int buf = k & 1;
        // issue next tile's loads (in flight during compute below)
        if (k + 1 < NT) {
            const size_t row = rowbase + (k + 1) * TTILE + li;
            r_dt = *reinterpret_cast<const float2*>(&dt [row * 2048 + e0 + lj]);
            r_xc = *reinterpret_cast<const float2*>(&xc [row * 2048 + e0 + lj]);
            r_z  = *reinterpret_cast<const float2*>(&xz [row * 4096 + 2048 + e0 + lj]);
            r_B  = *reinterpret_cast<const float2*>(&xdbl[row * 96 + 64 + lj]);
            r_C  = *reinterpret_cast<const float2*>(&xdbl[row * 96 + 80 + lj]);
        }
        // compute current tile from LDS
#pragma unroll
        for (int i = 0; i < TTILE; i++) {
            const float dtv = s_dt[buf][i][c];
            const float xv  = s_xc[buf][i][c];
            const float Bv  = s_B [buf][i][s];
            const float Cv  = s_C [buf][i][s];
            h = __expf(dtv * a) * h + dtv * Bv * xv;
            float p = h * Cv;
            p += __shfl_xor(p, 1, 16);
            p += __shfl_xor(p, 2, 16);
            p += __shfl_xor(p, 4, 16);
            p += __shfl_xor(p, 8, 16);
            if (s == 0) {
                const float z = s_z[buf][i][c];
                s_y[i][c] = (p + dcoef * xv) * (z / (1.f + __expf(-z)));
            }
        }
        __syncthreads();   // s_y complete; all reads of buf done
        // flush y tile (coalesced float2)
        {
            const size_t row = rowbase + k * TTILE + li;
            *reinterpret_cast<float2*>(&xz[row * 4096 + e0 + lj]) =
                *reinterpret_cast<const float2*>(&s_y[li][lj]);
        }
        // commit next tile into alternate buffer
        if (k + 1 < NT) {
            const int nb = (k + 1) & 1;
            *reinterpret_cast<float2*>(&s_dt[nb][li][lj]) = r_dt;
            *reinterpret_cast<float2*>(&s_xc[nb][li][lj]) = r_xc;
            *reinterpret_cast<float2*>(&s_z [nb][li][lj]) = r_z;
            *reinterpret_cast<float2*>(&s_B [nb][li][lj]) = r_B;
            *reinterpret_cast<float2*>(&s_C [nb][li][lj]) = r_C;
        }
        __syncthreads();   // commits + y flush visible before next iteration
    }
}

extern "C" void kernel_launch(void* const* d_in, const int* in_sizes, int n_in,
                              void* d_out, int out_size, void* d_ws, size_t ws_size,
                              hipStream_t stream)
{
    const float* x_f    = (const float*)d_in[0];
    const float* x_h    = (const float*)d_in[1];
    const float* W_hf   = (const float*)d_in[2];
    const float* b_hf   = (const float*)d_in[3];
    const float* W_in   = (const float*)d_in[4];
    const float* conv_w = (const float*)d_in[5];
    const float* conv_b = (const float*)d_in[6];
    const float* W_x    = (const float*)d_in[7];
    const float* W_dt   = (const float*)d_in[8];
    const float* b_dt   = (const float*)d_in[9];
    const float* A_log  = (const float*)d_in[10];
    const float* Dw     = (const float*)d_in[11];
    const float* W_out  = (const float*)d_in[12];
    float* out = (float*)d_out;
    float* ws  = (float*)d_ws;

    // Workspace layout (floats). m region is reused for split-K partials+x_dbl
    // after m is consumed by GEMM-in.
    float* m    = ws;                    // 4,194,304 f
    float* xz   = ws + 4194304;          // 16,777,216 f  (x_in | z; later y | z)
    float* xc   = ws + 20971520;         // 8,388,608 f
    float* dt   = ws + 29360128;         // 8,388,608 f
    float* part = ws;                    // 8 * 4096 * 96 = 3,145,728 f (over m)
    float* xdbl = ws + 3145728;          // 393,216 f (still inside m region)
    // total: 37,748,736 floats = 151 MB

    const int M = MROWS;

    // 1. m = x_f * sigmoid(x_h @ W_hf^T + b_hf)
    gemm_tiled<1><<<dim3(DMODEL / 128, M / 128, 1), 256, 0, stream>>>(
        x_h, DMODEL, W_hf, DMODEL, m, DMODEL, M, DMODEL, DMODEL,
        b_hf, x_f, 0, DMODEL);

    // 2. xz = m @ W_in^T   (N = 4096)
    gemm_tiled<0><<<dim3(4096 / 128, M / 128, 1), 256, 0, stream>>>(
        m, DMODEL, W_in, DMODEL, xz, 4096, M, 4096, DMODEL,
        nullptr, nullptr, 0, DMODEL);

    // 3. x_c = silu(causal_conv4(x_in) + conv_b)
    conv_silu_kernel<<<(M * DINNER) / 256, 256, 0, stream>>>(xz, conv_w, conv_b, xc);

    // 4. x_dbl partials = x_c @ W_x^T  (N=96, split-K 8x256)
    gemm_tiled<0><<<dim3(1, M / 128, 8), 256, 0, stream>>>(
        xc, DINNER, W_x, DINNER, part, NDBL, M, NDBL, DINNER,
        nullptr, nullptr, 0, 256);
    reduce_splitk<<<(M * NDBL + 255) / 256, 256, 0, stream>>>(
        part, xdbl, M * NDBL, 8, (size_t)M * NDBL);

    // 5. dt = softplus(x_dbl[:, :64] @ W_dt^T + b_dt)
    gemm_tiled<2><<<dim3(DINNER / 128, M / 128, 1), 256, 0, stream>>>(
        xdbl, NDBL, W_dt, DTRANK, dt, DINNER, M, DINNER, DTRANK,
        b_dt, nullptr, 0, DTRANK);

    // 6. scan + skip + gating; writes y into xz cols [0,2048)
    scan_kernel<<<(BATCH * DINNER) / 16, 256, 0, stream>>>(
        dt, xc, xdbl, xz, A_log, Dw);

    // 7. out = y @ W_out^T
    gemm_tiled<0><<<dim3(DMODEL / 128, M / 128, 1), 256, 0, stream>>>(
        xz, 4096, W_out, DINNER, out, DMODEL, M, DMODEL, DINNER,
        nullptr, nullptr, 0, DINNER);
}

// Round 3
// 1156.934 us; speedup vs baseline: 2.2481x; 1.3448x over previous
//
#include <hip/hip_runtime.h>
#include <math.h>

#define L_SEQ  2048
#define BATCH  2
#define DMODEL 1024
#define DINNER 2048
#define DSTATE 16
#define DTRANK 64
#define NDBL   96
#define MROWS  (BATCH * L_SEQ)   // 4096
#define NCHUNK 8
#define LCH    (L_SEQ / NCHUNK)  // 256
#define TTILE  32
#define NTILE  (LCH / TTILE)     // 8

// ---------------------------------------------------------------------------
// Tiled fp32 GEMM: C[M,N](ldc) = epi(A[M,K](lda) @ B[N,K](ldb)^T)
// ---------------------------------------------------------------------------
template <int EPI>
__global__ __launch_bounds__(256) void gemm_tiled(
    const float* __restrict__ A, int lda,
    const float* __restrict__ Bw, int ldb,
    float* __restrict__ C, int ldc,
    int M, int N, int K,
    const float* __restrict__ bias,
    const float* __restrict__ mul,
    int k0, int ksz)
{
    __shared__ float As[16][132];
    __shared__ float Bs[16][132];
    const int tid = threadIdx.x;
    const int tx = tid & 15;
    const int ty = tid >> 4;
    const int row0 = blockIdx.y * 128;
    const int col0 = blockIdx.x * 128;
    const int kk0 = k0 + blockIdx.z * ksz;
    float* Cz = C + (size_t)blockIdx.z * (size_t)M * (size_t)ldc;

    float acc[8][8];
#pragma unroll
    for (int i = 0; i < 8; i++)
#pragma unroll
        for (int j = 0; j < 8; j++) acc[i][j] = 0.f;

    for (int kt = kk0; kt < kk0 + ksz; kt += 16) {
#pragma unroll
        for (int rep = 0; rep < 2; rep++) {
            int idx = rep * 256 + tid;
            int i = idx >> 2;
            int kq = (idx & 3) * 4;
            const float4 v = *reinterpret_cast<const float4*>(
                &A[(size_t)(row0 + i) * lda + kt + kq]);
            As[kq + 0][i] = v.x; As[kq + 1][i] = v.y;
            As[kq + 2][i] = v.z; As[kq + 3][i] = v.w;
        }
#pragma unroll
        for (int rep = 0; rep < 2; rep++) {
            int idx = rep * 256 + tid;
            int j = idx >> 2;
            int kq = (idx & 3) * 4;
            float4 v = make_float4(0.f, 0.f, 0.f, 0.f);
            if (col0 + j < N)
                v = *reinterpret_cast<const float4*>(
                    &Bw[(size_t)(col0 + j) * ldb + kt + kq]);
            Bs[kq + 0][j] = v.x; Bs[kq + 1][j] = v.y;
            Bs[kq + 2][j] = v.z; Bs[kq + 3][j] = v.w;
        }
        __syncthreads();
#pragma unroll
        for (int k = 0; k < 16; k++) {
            float a[8], b[8];
#pragma unroll
            for (int i = 0; i < 8; i++) a[i] = As[k][ty * 8 + i];
#pragma unroll
            for (int j = 0; j < 8; j++) b[j] = Bs[k][tx * 8 + j];
#pragma unroll
            for (int i = 0; i < 8; i++)
#pragma unroll
                for (int j = 0; j < 8; j++)
                    acc[i][j] = fmaf(a[i], b[j], acc[i][j]);
        }
        __syncthreads();
    }

#pragma unroll
    for (int i = 0; i < 8; i++) {
        int r = row0 + ty * 8 + i;
#pragma unroll
        for (int j = 0; j < 8; j++) {
            int c = col0 + tx * 8 + j;
            if (c < N) {
                float v = acc[i][j];
                if (EPI == 1) {
                    v = 1.f / (1.f + __expf(-(v + bias[c])));
                    v *= mul[(size_t)r * N + c];
                } else if (EPI == 2) {
                    v += bias[c];
                    v = (v > 20.f) ? v : log1pf(__expf(v));
                }
                Cz[(size_t)r * ldc + c] = v;
            }
        }
    }
}

// Fixed-order split-K reduction (deterministic).
__global__ __launch_bounds__(256) void reduce_splitk(
    const float* __restrict__ part, float* __restrict__ out,
    int n, int nsplit, size_t stride)
{
    int i = blockIdx.x * 256 + threadIdx.x;
    if (i < n) {
        float s = 0.f;
        for (int j = 0; j < nsplit; j++) s += part[(size_t)j * stride + i];
        out[i] = s;
    }
}

// Depthwise causal conv (width 4) + bias + SiLU.
__global__ __launch_bounds__(256) void conv_silu_kernel(
    const float* __restrict__ xz, const float* __restrict__ cw,
    const float* __restrict__ cb, float* __restrict__ xc)
{
    int gid = blockIdx.x * 256 + threadIdx.x;   // M * DINNER threads
    int e = gid & (DINNER - 1);
    int row = gid >> 11;
    int t = row & (L_SEQ - 1);
    float s = cb[e];
#pragma unroll
    for (int j = 0; j < 4; j++) {
        int tt = t - 3 + j;
        if (tt >= 0)
            s = fmaf(cw[e * 4 + j], xz[(size_t)(row - 3 + j) * 4096 + e], s);
    }
    xc[(size_t)row * 2048 + e] = s / (1.f + __expf(-s));
}

// DPP-based in-wave add: x += x shuffled by CTRL (within 16-lane row).
// 0xB1=quad_perm xor1, 0x4E=quad_perm xor2, 0x124=row_ror:4, 0x128=row_ror:8.
template <int CTRL>
__device__ __forceinline__ float dpp_add(float x) {
    int xi = __builtin_bit_cast(int, x);
    int yi = __builtin_amdgcn_update_dpp(xi, xi, CTRL, 0xF, 0xF, true);
    return x + __builtin_bit_cast(float, yi);
}

// ---------------------------------------------------------------------------
// Chunked selective scan: h_t = exp(dt*a)*h + dt*B*x is linear in h, so split
// L into NCHUNK chunks; pass A: per-chunk local scan from 0 + decay product;
// pass B: tiny sequential combine -> per-chunk h0; pass C: recompute with h0,
// emit gated y. Block = 16 channels x 16 states; LDS transposed [ch][t] pad36
// for b128 reads; 16-state reduce via 4 DPP VALU adds (no LDS pipe).
// ---------------------------------------------------------------------------
__global__ __launch_bounds__(256) void scan_pass_a(
    const float* __restrict__ dt, const float* __restrict__ xc,
    const float* __restrict__ xdbl, const float* __restrict__ A_log,
    float* __restrict__ hloc, float* __restrict__ Pp)
{
    __shared__ float s_dt[2][16][36];
    __shared__ float s_xc[2][16][36];
    __shared__ float s_B [2][16][36];
    const int tid = threadIdx.x;
    const int e0 = blockIdx.x << 4;
    const int chunk = blockIdx.y;          // 0..NCHUNK-2
    const int b = blockIdx.z;
    const int li = tid >> 3, lj = (tid & 7) << 1;
    const int c = tid >> 4, s = tid & 15;
    const float a = -__expf(A_log[(e0 + c) * DSTATE + s]);
    const size_t row0 = (size_t)b * L_SEQ + (size_t)chunk * LCH;

    float2 r_dt, r_xc, r_B;
    {
        const size_t row = row0 + li;
        r_dt = *(const float2*)&dt[row * 2048 + e0 + lj];
        r_xc = *(const float2*)&xc[row * 2048 + e0 + lj];
        r_B  = *(const float2*)&xdbl[row * 96 + 64 + lj];
        s_dt[0][lj][li] = r_dt.x; s_dt[0][lj + 1][li] = r_dt.y;
        s_xc[0][lj][li] = r_xc.x; s_xc[0][lj + 1][li] = r_xc.y;
        s_B [0][lj][li] = r_B.x;  s_B [0][lj + 1][li] = r_B.y;
    }
    __syncthreads();

    float h = 0.f, sdt = 0.f;
    for (int k = 0; k < NTILE; k++) {
        const int buf = k & 1;
        if (k + 1 < NTILE) {
            const size_t row = row0 + (k + 1) * TTILE + li;
            r_dt = *(const float2*)&dt[row * 2048 + e0 + lj];
            r_xc = *(const float2*)&xc[row * 2048 + e0 + lj];
            r_B  = *(const float2*)&xdbl[row * 96 + 64 + lj];
        }
#pragma unroll
        for (int jj = 0; jj < 8; jj++) {
            const float4 d4 = *(const float4*)&s_dt[buf][c][jj * 4];
            const float4 x4 = *(const float4*)&s_xc[buf][c][jj * 4];
            const float4 B4 = *(const float4*)&s_B [buf][s][jj * 4];
#pragma unroll
            for (int j = 0; j < 4; j++) {
                const float dtv = ((const float*)&d4)[j];
                const float xv  = ((const float*)&x4)[j];
                const float Bv  = ((const float*)&B4)[j];
                h = fmaf(__expf(dtv * a), h, dtv * Bv * xv);
                sdt += dtv;
            }
        }
        if (k + 1 < NTILE) {
            const int nb = (k + 1) & 1;
            s_dt[nb][lj][li] = r_dt.x; s_dt[nb][lj + 1][li] = r_dt.y;
            s_xc[nb][lj][li] = r_xc.x; s_xc[nb][lj + 1][li] = r_xc.y;
            s_B [nb][lj][li] = r_B.x;  s_B [nb][lj + 1][li] = r_B.y;
            __syncthreads();
        }
    }
    // chunk-major layout: coalesced here, in pass B, and in pass C
    const size_t o = (size_t)chunk * (BATCH * DINNER * DSTATE)
                   + ((size_t)(b * DINNER + e0 + c) * DSTATE + s);
    hloc[o] = h;
    Pp[o] = __expf(a * sdt);
}

__global__ __launch_bounds__(256) void scan_pass_b(
    const float* __restrict__ hloc, const float* __restrict__ Pp,
    float* __restrict__ h0)
{
    const int idx = blockIdx.x * 256 + threadIdx.x;   // 65536 = B*DINNER*DSTATE
    const int STRIDE = BATCH * DINNER * DSTATE;
    float h = 0.f;
    h0[idx] = 0.f;
    for (int c = 0; c < NCHUNK - 1; c++) {
        h = fmaf(Pp[(size_t)c * STRIDE + idx], h, hloc[(size_t)c * STRIDE + idx]);
        h0[(size_t)(c + 1) * STRIDE + idx] = h;
    }
}

__global__ __launch_bounds__(256) void scan_pass_c(
    const float* __restrict__ dt, const float* __restrict__ xc,
    const float* __restrict__ xdbl, float* __restrict__ xz,
    const float* __restrict__ A_log, const float* __restrict__ Dw,
    const float* __restrict__ h0)
{
    __shared__ float s_dt[2][16][36];
    __shared__ float s_xc[2][16][36];
    __shared__ float s_B [2][16][36];
    __shared__ float s_C [2][16][36];
    __shared__ float s_y [TTILE][16];
    const int tid = threadIdx.x;
    const int e0 = blockIdx.x << 4;
    const int chunk = blockIdx.y;
    const int b = blockIdx.z;
    const int li = tid >> 3, lj = (tid & 7) << 1;
    const int c = tid >> 4, s = tid & 15;
    const float a = -__expf(A_log[(e0 + c) * DSTATE + s]);
    const float df0 = Dw[e0 + lj], df1 = Dw[e0 + lj + 1];
    const size_t row0 = (size_t)b * L_SEQ + (size_t)chunk * LCH;

    float2 r_dt, r_xc, r_B, r_C, rz_nxt;
    float2 rz_cur;
    {
        const size_t row = row0 + li;
        r_dt = *(const float2*)&dt[row * 2048 + e0 + lj];
        r_xc = *(const float2*)&xc[row * 2048 + e0 + lj];
        r_B  = *(const float2*)&xdbl[row * 96 + 64 + lj];
        r_C  = *(const float2*)&xdbl[row * 96 + 80 + lj];
        rz_cur = *(const float2*)&xz[row * 4096 + 2048 + e0 + lj];
        s_dt[0][lj][li] = r_dt.x; s_dt[0][lj + 1][li] = r_dt.y;
        s_xc[0][lj][li] = r_xc.x; s_xc[0][lj + 1][li] = r_xc.y;
        s_B [0][lj][li] = r_B.x;  s_B [0][lj + 1][li] = r_B.y;
        s_C [0][lj][li] = r_C.x;  s_C [0][lj + 1][li] = r_C.y;
    }
    __syncthreads();

    float h = h0[(size_t)chunk * (BATCH * DINNER * DSTATE)
               + ((size_t)(b * DINNER + e0 + c) * DSTATE + s)];

    for (int k = 0; k < NTILE; k++) {
        const int buf = k & 1;
        if (k + 1 < NTILE) {
            const size_t row = row0 + (k + 1) * TTILE + li;
            r_dt = *(const float2*)&dt[row * 2048 + e0 + lj];
            r_xc = *(const float2*)&xc[row * 2048 + e0 + lj];
            r_B  = *(const float2*)&xdbl[row * 96 + 64 + lj];
            r_C  = *(const float2*)&xdbl[row * 96 + 80 + lj];
            rz_nxt = *(const float2*)&xz[row * 4096 + 2048 + e0 + lj];
        }
#pragma unroll
        for (int jj = 0; jj < 8; jj++) {
            const float4 d4 = *(const float4*)&s_dt[buf][c][jj * 4];
            const float4 x4 = *(const float4*)&s_xc[buf][c][jj * 4];
            const float4 B4 = *(const float4*)&s_B [buf][s][jj * 4];
            const float4 C4 = *(const float4*)&s_C [buf][s][jj * 4];
#pragma unroll
            for (int j = 0; j < 4; j++) {
                const float dtv = ((const float*)&d4)[j];
                const float xv  = ((const float*)&x4)[j];
                const float Bv  = ((const float*)&B4)[j];
                const float Cv  = ((const float*)&C4)[j];
                h = fmaf(__expf(dtv * a), h, dtv * Bv * xv);
                float p = h * Cv;
                p = dpp_add<0xB1>(p);
                p = dpp_add<0x4E>(p);
                p = dpp_add<0x124>(p);
                p = dpp_add<0x128>(p);
                if (s == 0) s_y[jj * 4 + j][c] = p;
            }
        }
        __syncthreads();   // s_y ready; all reads of buf done
        {
            const size_t row = row0 + k * TTILE + li;
            const float xv0 = s_xc[buf][lj][li];
            const float xv1 = s_xc[buf][lj + 1][li];
            const float y0 = (s_y[li][lj] + df0 * xv0)
                           * (rz_cur.x / (1.f + __expf(-rz_cur.x)));
            const float y1 = (s_y[li][lj + 1] + df1 * xv1)
                           * (rz_cur.y / (1.f + __expf(-rz_cur.y)));
            *(float2*)&xz[row * 4096 + e0 + lj] = make_float2(y0, y1);
        }
        if (k + 1 < NTILE) {
            const int nb = (k + 1) & 1;
            s_dt[nb][lj][li] = r_dt.x; s_dt[nb][lj + 1][li] = r_dt.y;
            s_xc[nb][lj][li] = r_xc.x; s_xc[nb][lj + 1][li] = r_xc.y;
            s_B [nb][lj][li] = r_B.x;  s_B [nb][lj + 1][li] = r_B.y;
            s_C [nb][lj][li] = r_C.x;  s_C [nb][lj + 1][li] = r_C.y;
            rz_cur = rz_nxt;
        }
        __syncthreads();   // commits + s_y flush reads complete
    }
}

extern "C" void kernel_launch(void* const* d_in, const int* in_sizes, int n_in,
                              void* d_out, int out_size, void* d_ws, size_t ws_size,
                              hipStream_t stream)
{
    const float* x_f    = (const float*)d_in[0];
    const float* x_h    = (const float*)d_in[1];
    const float* W_hf   = (const float*)d_in[2];
    const float* b_hf   = (const float*)d_in[3];
    const float* W_in   = (const float*)d_in[4];
    const float* conv_w = (const float*)d_in[5];
    const float* conv_b = (const float*)d_in[6];
    const float* W_x    = (const float*)d_in[7];
    const float* W_dt   = (const float*)d_in[8];
    const float* b_dt   = (const float*)d_in[9];
    const float* A_log  = (const float*)d_in[10];
    const float* Dw     = (const float*)d_in[11];
    const float* W_out  = (const float*)d_in[12];
    float* out = (float*)d_out;
    float* ws  = (float*)d_ws;

    // Workspace (floats). m region [0, 4194304) is reused twice after GEMM-2:
    //   GEMM-4 phase: part [0, 3145728) + xdbl [3145728, 3538944)
    //   scan phase:   hloc [0, 524288) + P [524288, 1048576) + h0 [1048576, 1572864)
    //                 (xdbl still live at 3145728+)
    float* m    = ws;
    float* xz   = ws + 4194304;          // 16,777,216 f  (x_in | z; later y | z)
    float* xc   = ws + 20971520;         // 8,388,608 f
    float* dt   = ws + 29360128;         // 8,388,608 f
    float* part = ws;
    float* xdbl = ws + 3145728;
    float* hloc = ws;
    float* Pp   = ws + 524288;
    float* h0   = ws + 1048576;

    const int M = MROWS;

    // 1. m = x_f * sigmoid(x_h @ W_hf^T + b_hf)
    gemm_tiled<1><<<dim3(DMODEL / 128, M / 128, 1), 256, 0, stream>>>(
        x_h, DMODEL, W_hf, DMODEL, m, DMODEL, M, DMODEL, DMODEL,
        b_hf, x_f, 0, DMODEL);

    // 2. xz = m @ W_in^T
    gemm_tiled<0><<<dim3(4096 / 128, M / 128, 1), 256, 0, stream>>>(
        m, DMODEL, W_in, DMODEL, xz, 4096, M, 4096, DMODEL,
        nullptr, nullptr, 0, DMODEL);

    // 3. x_c = silu(causal_conv4(x_in) + conv_b)
    conv_silu_kernel<<<(M * DINNER) / 256, 256, 0, stream>>>(xz, conv_w, conv_b, xc);

    // 4. x_dbl = x_c @ W_x^T  (split-K)
    gemm_tiled<0><<<dim3(1, M / 128, 8), 256, 0, stream>>>(
        xc, DINNER, W_x, DINNER, part, NDBL, M, NDBL, DINNER,
        nullptr, nullptr, 0, 256);
    reduce_splitk<<<(M * NDBL + 255) / 256, 256, 0, stream>>>(
        part, xdbl, M * NDBL, 8, (size_t)M * NDBL);

    // 5. dt = softplus(x_dbl[:, :64] @ W_dt^T + b_dt)
    gemm_tiled<2><<<dim3(DINNER / 128, M / 128, 1), 256, 0, stream>>>(
        xdbl, NDBL, W_dt, DTRANK, dt, DINNER, M, DINNER, DTRANK,
        b_dt, nullptr, 0, DTRANK);

    // 6. chunked scan
    scan_pass_a<<<dim3(DINNER / 16, NCHUNK - 1, BATCH), 256, 0, stream>>>(
        dt, xc, xdbl, A_log, hloc, Pp);
    scan_pass_b<<<(BATCH * DINNER * DSTATE) / 256, 256, 0, stream>>>(hloc, Pp, h0);
    scan_pass_c<<<dim3(DINNER / 16, NCHUNK, BATCH), 256, 0, stream>>>(
        dt, xc, xdbl, xz, A_log, Dw, h0);

    // 7. out = y @ W_out^T
    gemm_tiled<0><<<dim3(DMODEL / 128, M / 128, 1), 256, 0, stream>>>(
        xz, 4096, W_out, DINNER, out, DMODEL, M, DMODEL, DINNER,
        nullptr, nullptr, 0, DINNER);
}

// Round 4
// 389.348 us; speedup vs baseline: 6.6801x; 2.9715x over previous
//
#include <hip/hip_runtime.h>
#include <hip/hip_bf16.h>
#include <math.h>

#define L_SEQ  2048
#define BATCH  2
#define DMODEL 1024
#define DINNER 2048
#define DSTATE 16
#define DTRANK 64
#define NDBL   96
#define MROWS  (BATCH * L_SEQ)   // 4096
#define NCHUNK 8
#define LCH    (L_SEQ / NCHUNK)  // 256
#define TTILE  32
#define NTILE  (LCH / TTILE)     // 8

typedef __attribute__((ext_vector_type(8))) short bf16x8;
typedef __attribute__((ext_vector_type(4))) float f32x4;

__device__ __forceinline__ unsigned short f2bu(float x) {
    __hip_bfloat16 h = __float2bfloat16(x);
    return __builtin_bit_cast(unsigned short, h);
}

// ---------------------------------------------------------------------------
// fp32 -> bf16 conversion pass (one-time, for weights / x_h). n % 1024 == 0.
// ---------------------------------------------------------------------------
__global__ __launch_bounds__(256) void cvt_bf16(
    const float* __restrict__ s, __hip_bfloat16* __restrict__ d)
{
    const int i = (blockIdx.x * 256 + threadIdx.x) * 4;
    const float4 v = *reinterpret_cast<const float4*>(&s[i]);
    ushort4 u;
    u.x = f2bu(v.x); u.y = f2bu(v.y); u.z = f2bu(v.z); u.w = f2bu(v.w);
    *reinterpret_cast<ushort4*>(&d[i]) = u;
}

// ---------------------------------------------------------------------------
// MFMA bf16 GEMM: C[M,N] = epi(A[M,K](lda) @ Bw[N,K](ldb)^T), 128x128 tile,
// BK=32, 256 threads = 4 waves (2x2), each wave 64x64 via 4x4 16x16x32 MFMA.
// A,B staged via global_load_lds (16B) into linear LDS [128][32] bf16.
// EPI: 0 = fp32 C; 1 = bf16 C = sigmoid(acc+bias)*mul; 2 = split fp32
//      (col<2048 -> Cf stride 2048, else C2 stride 2048).
// M,N,K all multiples of 128/128/32; no masking.
// ---------------------------------------------------------------------------
template <int EPI>
__global__ __launch_bounds__(256) void mfma_gemm(
    const __hip_bfloat16* __restrict__ A, int lda,
    const __hip_bfloat16* __restrict__ Bw, int ldb,
    int K,
    float* __restrict__ Cf, int ldc,
    __hip_bfloat16* __restrict__ Cb,
    float* __restrict__ C2,
    const float* __restrict__ bias,
    const float* __restrict__ mul, int ldmul)
{
    __shared__ unsigned short As[128 * 32];
    __shared__ unsigned short Bs[128 * 32];
    const int tid = threadIdx.x;
    const int row0 = blockIdx.y * 128;
    const int col0 = blockIdx.x * 128;
    const int wid = tid >> 6, lane = tid & 63;
    const int wr = wid >> 1, wc = wid & 1;
    const int fr = lane & 15, fq = lane >> 4;

    f32x4 acc[4][4];
#pragma unroll
    for (int i = 0; i < 4; i++)
#pragma unroll
        for (int j = 0; j < 4; j++) acc[i][j] = (f32x4){0.f, 0.f, 0.f, 0.f};

    // staging item mapping: item i covers LDS row i>>2, 8-elem slot i&3
    const int i0 = tid, i1 = tid + 256;
    const size_t ga0 = (size_t)(row0 + (i0 >> 2)) * lda + (i0 & 3) * 8;
    const size_t ga1 = (size_t)(row0 + (i1 >> 2)) * lda + (i1 & 3) * 8;
    const size_t gb0 = (size_t)(col0 + (i0 >> 2)) * ldb + (i0 & 3) * 8;
    const size_t gb1 = (size_t)(col0 + (i1 >> 2)) * ldb + (i1 & 3) * 8;

    for (int kt = 0; kt < K; kt += 32) {
#if __has_builtin(__builtin_amdgcn_global_load_lds)
        __syncthreads();   // all reads of previous tile complete
        __builtin_amdgcn_global_load_lds(
            (const __attribute__((address_space(1))) unsigned int*)(A + ga0 + kt),
            (__attribute__((address_space(3))) unsigned int*)&As[i0 * 8], 16, 0, 0);
        __builtin_amdgcn_global_load_lds(
            (const __attribute__((address_space(1))) unsigned int*)(A + ga1 + kt),
            (__attribute__((address_space(3))) unsigned int*)&As[i1 * 8], 16, 0, 0);
        __builtin_amdgcn_global_load_lds(
            (const __attribute__((address_space(1))) unsigned int*)(Bw + gb0 + kt),
            (__attribute__((address_space(3))) unsigned int*)&Bs[i0 * 8], 16, 0, 0);
        __builtin_amdgcn_global_load_lds(
            (const __attribute__((address_space(1))) unsigned int*)(Bw + gb1 + kt),
            (__attribute__((address_space(3))) unsigned int*)&Bs[i1 * 8], 16, 0, 0);
        __syncthreads();   // compiler drains vmcnt before barrier; tile visible
#else
        const uint4 va0 = *reinterpret_cast<const uint4*>(A + ga0 + kt);
        const uint4 va1 = *reinterpret_cast<const uint4*>(A + ga1 + kt);
        const uint4 vb0 = *reinterpret_cast<const uint4*>(Bw + gb0 + kt);
        const uint4 vb1 = *reinterpret_cast<const uint4*>(Bw + gb1 + kt);
        __syncthreads();
        *reinterpret_cast<uint4*>(&As[i0 * 8]) = va0;
        *reinterpret_cast<uint4*>(&As[i1 * 8]) = va1;
        *reinterpret_cast<uint4*>(&Bs[i0 * 8]) = vb0;
        *reinterpret_cast<uint4*>(&Bs[i1 * 8]) = vb1;
        __syncthreads();
#endif
        bf16x8 af[4], bf[4];
#pragma unroll
        for (int rb = 0; rb < 4; rb++)
            af[rb] = *reinterpret_cast<const bf16x8*>(
                &As[(wr * 64 + rb * 16 + fr) * 32 + fq * 8]);
#pragma unroll
        for (int cb = 0; cb < 4; cb++)
            bf[cb] = *reinterpret_cast<const bf16x8*>(
                &Bs[(wc * 64 + cb * 16 + fr) * 32 + fq * 8]);
#pragma unroll
        for (int rb = 0; rb < 4; rb++)
#pragma unroll
            for (int cb = 0; cb < 4; cb++)
                acc[rb][cb] = __builtin_amdgcn_mfma_f32_16x16x32_bf16(
                    af[rb], bf[cb], acc[rb][cb], 0, 0, 0);
    }

    // C/D layout: col = lane&15, row = (lane>>4)*4 + reg  [m89-verified]
    const int r0 = row0 + wr * 64, c0 = col0 + wc * 64;
#pragma unroll
    for (int rb = 0; rb < 4; rb++)
#pragma unroll
        for (int cb = 0; cb < 4; cb++) {
            const int col = c0 + cb * 16 + fr;
#pragma unroll
            for (int j = 0; j < 4; j++) {
                const int row = r0 + rb * 16 + fq * 4 + j;
                float v = acc[rb][cb][j];
                if (EPI == 0) {
                    Cf[(size_t)row * ldc + col] = v;
                } else if (EPI == 1) {
                    v = 1.f / (1.f + __expf(-(v + bias[col])));
                    v *= mul[(size_t)row * ldmul + col];
                    Cb[(size_t)row * ldc + col] = __float2bfloat16(v);
                } else {
                    if (col0 < 2048) Cf[(size_t)row * 2048 + col] = v;
                    else             C2[(size_t)row * 2048 + col - 2048] = v;
                }
            }
        }
}

// ---------------------------------------------------------------------------
// Tiled fp32 GEMM (kept for the small GEMM-4/GEMM-5): C = epi(A @ Bw^T)
// ---------------------------------------------------------------------------
template <int EPI>
__global__ __launch_bounds__(256) void gemm_tiled(
    const float* __restrict__ A, int lda,
    const float* __restrict__ Bw, int ldb,
    float* __restrict__ C, int ldc,
    int M, int N, int K,
    const float* __restrict__ bias,
    const float* __restrict__ mul,
    int k0, int ksz)
{
    __shared__ float As[16][132];
    __shared__ float Bs[16][132];
    const int tid = threadIdx.x;
    const int tx = tid & 15;
    const int ty = tid >> 4;
    const int row0 = blockIdx.y * 128;
    const int col0 = blockIdx.x * 128;
    const int kk0 = k0 + blockIdx.z * ksz;
    float* Cz = C + (size_t)blockIdx.z * (size_t)M * (size_t)ldc;

    float acc[8][8];
#pragma unroll
    for (int i = 0; i < 8; i++)
#pragma unroll
        for (int j = 0; j < 8; j++) acc[i][j] = 0.f;

    for (int kt = kk0; kt < kk0 + ksz; kt += 16) {
#pragma unroll
        for (int rep = 0; rep < 2; rep++) {
            int idx = rep * 256 + tid;
            int i = idx >> 2;
            int kq = (idx & 3) * 4;
            const float4 v = *reinterpret_cast<const float4*>(
                &A[(size_t)(row0 + i) * lda + kt + kq]);
            As[kq + 0][i] = v.x; As[kq + 1][i] = v.y;
            As[kq + 2][i] = v.z; As[kq + 3][i] = v.w;
        }
#pragma unroll
        for (int rep = 0; rep < 2; rep++) {
            int idx = rep * 256 + tid;
            int j = idx >> 2;
            int kq = (idx & 3) * 4;
            float4 v = make_float4(0.f, 0.f, 0.f, 0.f);
            if (col0 + j < N)
                v = *reinterpret_cast<const float4*>(
                    &Bw[(size_t)(col0 + j) * ldb + kt + kq]);
            Bs[kq + 0][j] = v.x; Bs[kq + 1][j] = v.y;
            Bs[kq + 2][j] = v.z; Bs[kq + 3][j] = v.w;
        }
        __syncthreads();
#pragma unroll
        for (int k = 0; k < 16; k++) {
            float a[8], b[8];
#pragma unroll
            for (int i = 0; i < 8; i++) a[i] = As[k][ty * 8 + i];
#pragma unroll
            for (int j = 0; j < 8; j++) b[j] = Bs[k][tx * 8 + j];
#pragma unroll
            for (int i = 0; i < 8; i++)
#pragma unroll
                for (int j = 0; j < 8; j++)
                    acc[i][j] = fmaf(a[i], b[j], acc[i][j]);
        }
        __syncthreads();
    }

#pragma unroll
    for (int i = 0; i < 8; i++) {
        int r = row0 + ty * 8 + i;
#pragma unroll
        for (int j = 0; j < 8; j++) {
            int c = col0 + tx * 8 + j;
            if (c < N) {
                float v = acc[i][j];
                if (EPI == 2) {
                    v += bias[c];
                    v = (v > 20.f) ? v : log1pf(__expf(v));
                }
                Cz[(size_t)r * ldc + c] = v;
            }
        }
    }
}

// Fixed-order split-K reduction (deterministic).
__global__ __launch_bounds__(256) void reduce_splitk(
    const float* __restrict__ part, float* __restrict__ out,
    int n, int nsplit, size_t stride)
{
    int i = blockIdx.x * 256 + threadIdx.x;
    if (i < n) {
        float s = 0.f;
        for (int j = 0; j < nsplit; j++) s += part[(size_t)j * stride + i];
        out[i] = s;
    }
}

// Depthwise causal conv (width 4) + bias + SiLU. x_in plane stride 2048.
__global__ __launch_bounds__(256) void conv_silu_kernel(
    const float* __restrict__ x_in, const float* __restrict__ cw,
    const float* __restrict__ cb, float* __restrict__ xc)
{
    int gid = blockIdx.x * 256 + threadIdx.x;   // M * DINNER threads
    int e = gid & (DINNER - 1);
    int row = gid >> 11;
    int t = row & (L_SEQ - 1);
    float s = cb[e];
#pragma unroll
    for (int j = 0; j < 4; j++) {
        int tt = t - 3 + j;
        if (tt >= 0)
            s = fmaf(cw[e * 4 + j], x_in[(size_t)(row - 3 + j) * 2048 + e], s);
    }
    xc[(size_t)row * 2048 + e] = s / (1.f + __expf(-s));
}

// DPP-based in-wave add within 16-lane rows.
template <int CTRL>
__device__ __forceinline__ float dpp_add(float x) {
    int xi = __builtin_bit_cast(int, x);
    int yi = __builtin_amdgcn_update_dpp(xi, xi, CTRL, 0xF, 0xF, true);
    return x + __builtin_bit_cast(float, yi);
}

// ---------------------------------------------------------------------------
// Chunked selective scan (pass A: local scans; pass B: combine; pass C:
// recompute + gated y, emitted as bf16 for the MFMA out-projection).
// ---------------------------------------------------------------------------
__global__ __launch_bounds__(256) void scan_pass_a(
    const float* __restrict__ dt, const float* __restrict__ xc,
    const float* __restrict__ xdbl, const float* __restrict__ A_log,
    float* __restrict__ hloc, float* __restrict__ Pp)
{
    __shared__ float s_dt[2][16][36];
    __shared__ float s_xc[2][16][36];
    __shared__ float s_B [2][16][36];
    const int tid = threadIdx.x;
    const int e0 = blockIdx.x << 4;
    const int chunk = blockIdx.y;          // 0..NCHUNK-2
    const int b = blockIdx.z;
    const int li = tid >> 3, lj = (tid & 7) << 1;
    const int c = tid >> 4, s = tid & 15;
    const float a = -__expf(A_log[(e0 + c) * DSTATE + s]);
    const size_t row0 = (size_t)b * L_SEQ + (size_t)chunk * LCH;

    float2 r_dt, r_xc, r_B;
    {
        const size_t row = row0 + li;
        r_dt = *(const float2*)&dt[row * 2048 + e0 + lj];
        r_xc = *(const float2*)&xc[row * 2048 + e0 + lj];
        r_B  = *(const float2*)&xdbl[row * 96 + 64 + lj];
        s_dt[0][lj][li] = r_dt.x; s_dt[0][lj + 1][li] = r_dt.y;
        s_xc[0][lj][li] = r_xc.x; s_xc[0][lj + 1][li] = r_xc.y;
        s_B [0][lj][li] = r_B.x;  s_B [0][lj + 1][li] = r_B.y;
    }
    __syncthreads();

    float h = 0.f, sdt = 0.f;
    for (int k = 0; k < NTILE; k++) {
        const int buf = k & 1;
        if (k + 1 < NTILE) {
            const size_t row = row0 + (k + 1) * TTILE + li;
            r_dt = *(const float2*)&dt[row * 2048 + e0 + lj];
            r_xc = *(const float2*)&xc[row * 2048 + e0 + lj];
            r_B  = *(const float2*)&xdbl[row * 96 + 64 + lj];
        }
#pragma unroll
        for (int jj = 0; jj < 8; jj++) {
            const float4 d4 = *(const float4*)&s_dt[buf][c][jj * 4];
            const float4 x4 = *(const float4*)&s_xc[buf][c][jj * 4];
            const float4 B4 = *(const float4*)&s_B [buf][s][jj * 4];
#pragma unroll
            for (int j = 0; j < 4; j++) {
                const float dtv = ((const float*)&d4)[j];
                const float xv  = ((const float*)&x4)[j];
                const float Bv  = ((const float*)&B4)[j];
                h = fmaf(__expf(dtv * a), h, dtv * Bv * xv);
                sdt += dtv;
            }
        }
        if (k + 1 < NTILE) {
            const int nb = (k + 1) & 1;
            s_dt[nb][lj][li] = r_dt.x; s_dt[nb][lj + 1][li] = r_dt.y;
            s_xc[nb][lj][li] = r_xc.x; s_xc[nb][lj + 1][li] = r_xc.y;
            s_B [nb][lj][li] = r_B.x;  s_B [nb][lj + 1][li] = r_B.y;
            __syncthreads();
        }
    }
    const size_t o = (size_t)chunk * (BATCH * DINNER * DSTATE)
                   + ((size_t)(b * DINNER + e0 + c) * DSTATE + s);
    hloc[o] = h;
    Pp[o] = __expf(a * sdt);
}

__global__ __launch_bounds__(256) void scan_pass_b(
    const float* __restrict__ hloc, const float* __restrict__ Pp,
    float* __restrict__ h0)
{
    const int idx = blockIdx.x * 256 + threadIdx.x;   // 65536
    const int STRIDE = BATCH * DINNER * DSTATE;
    float h = 0.f;
    h0[idx] = 0.f;
    for (int c = 0; c < NCHUNK - 1; c++) {
        h = fmaf(Pp[(size_t)c * STRIDE + idx], h, hloc[(size_t)c * STRIDE + idx]);
        h0[(size_t)(c + 1) * STRIDE + idx] = h;
    }
}

__global__ __launch_bounds__(256) void scan_pass_c(
    const float* __restrict__ dt, const float* __restrict__ xc,
    const float* __restrict__ xdbl, const float* __restrict__ zp,
    __hip_bfloat16* __restrict__ yb,
    const float* __restrict__ A_log, const float* __restrict__ Dw,
    const float* __restrict__ h0)
{
    __shared__ float s_dt[2][16][36];
    __shared__ float s_xc[2][16][36];
    __shared__ float s_B [2][16][36];
    __shared__ float s_C [2][16][36];
    __shared__ float s_y [TTILE][16];
    const int tid = threadIdx.x;
    const int e0 = blockIdx.x << 4;
    const int chunk = blockIdx.y;
    const int b = blockIdx.z;
    const int li = tid >> 3, lj = (tid & 7) << 1;
    const int c = tid >> 4, s = tid & 15;
    const float a = -__expf(A_log[(e0 + c) * DSTATE + s]);
    const float df0 = Dw[e0 + lj], df1 = Dw[e0 + lj + 1];
    const size_t row0 = (size_t)b * L_SEQ + (size_t)chunk * LCH;

    float2 r_dt, r_xc, r_B, r_C, rz_nxt;
    float2 rz_cur;
    {
        const size_t row = row0 + li;
        r_dt = *(const float2*)&dt[row * 2048 + e0 + lj];
        r_xc = *(const float2*)&xc[row * 2048 + e0 + lj];
        r_B  = *(const float2*)&xdbl[row * 96 + 64 + lj];
        r_C  = *(const float2*)&xdbl[row * 96 + 80 + lj];
        rz_cur = *(const float2*)&zp[row * 2048 + e0 + lj];
        s_dt[0][lj][li] = r_dt.x; s_dt[0][lj + 1][li] = r_dt.y;
        s_xc[0][lj][li] = r_xc.x; s_xc[0][lj + 1][li] = r_xc.y;
        s_B [0][lj][li] = r_B.x;  s_B [0][lj + 1][li] = r_B.y;
        s_C [0][lj][li] = r_C.x;  s_C [0][lj + 1][li] = r_C.y;
    }
    __syncthreads();

    float h = h0[(size_t)chunk * (BATCH * DINNER * DSTATE)
               + ((size_t)(b * DINNER + e0 + c) * DSTATE + s)];

    for (int k = 0; k < NTILE; k++) {
        const int buf = k & 1;
        if (k + 1 < NTILE) {
            const size_t row = row0 + (k + 1) * TTILE + li;
            r_dt = *(const float2*)&dt[row * 2048 + e0 + lj];
            r_xc = *(const float2*)&xc[row * 2048 + e0 + lj];
            r_B  = *(const float2*)&xdbl[row * 96 + 64 + lj];
            r_C  = *(const float2*)&xdbl[row * 96 + 80 + lj];
            rz_nxt = *(const float2*)&zp[row * 2048 + e0 + lj];
        }
#pragma unroll
        for (int jj = 0; jj < 8; jj++) {
            const float4 d4 = *(const float4*)&s_dt[buf][c][jj * 4];
            const float4 x4 = *(const float4*)&s_xc[buf][c][jj * 4];
            const float4 B4 = *(const float4*)&s_B [buf][s][jj * 4];
            const float4 C4 = *(const float4*)&s_C [buf][s][jj * 4];
#pragma unroll
            for (int j = 0; j < 4; j++) {
                const float dtv = ((const float*)&d4)[j];
                const float xv  = ((const float*)&x4)[j];
                const float Bv  = ((const float*)&B4)[j];
                const float Cv  = ((const float*)&C4)[j];
                h = fmaf(__expf(dtv * a), h, dtv * Bv * xv);
                float p = h * Cv;
                p = dpp_add<0xB1>(p);
                p = dpp_add<0x4E>(p);
                p = dpp_add<0x124>(p);
                p = dpp_add<0x128>(p);
                if (s == 0) s_y[jj * 4 + j][c] = p;
            }
        }
        __syncthreads();
        {
            const size_t row = row0 + k * TTILE + li;
            const float xv0 = s_xc[buf][lj][li];
            const float xv1 = s_xc[buf][lj + 1][li];
            const float y0 = (s_y[li][lj] + df0 * xv0)
                           * (rz_cur.x / (1.f + __expf(-rz_cur.x)));
            const float y1 = (s_y[li][lj + 1] + df1 * xv1)
                           * (rz_cur.y / (1.f + __expf(-rz_cur.y)));
            __hip_bfloat162 yy;
            yy.x = __float2bfloat16(y0);
            yy.y = __float2bfloat16(y1);
            *reinterpret_cast<__hip_bfloat162*>(&yb[row * 2048 + e0 + lj]) = yy;
        }
        if (k + 1 < NTILE) {
            const int nb = (k + 1) & 1;
            s_dt[nb][lj][li] = r_dt.x; s_dt[nb][lj + 1][li] = r_dt.y;
            s_xc[nb][lj][li] = r_xc.x; s_xc[nb][lj + 1][li] = r_xc.y;
            s_B [nb][lj][li] = r_B.x;  s_B [nb][lj + 1][li] = r_B.y;
            s_C [nb][lj][li] = r_C.x;  s_C [nb][lj + 1][li] = r_C.y;
            rz_cur = rz_nxt;
        }
        __syncthreads();
    }
}

extern "C" void kernel_launch(void* const* d_in, const int* in_sizes, int n_in,
                              void* d_out, int out_size, void* d_ws, size_t ws_size,
                              hipStream_t stream)
{
    const float* x_f    = (const float*)d_in[0];
    const float* x_h    = (const float*)d_in[1];
    const float* W_hf   = (const float*)d_in[2];
    const float* b_hf   = (const float*)d_in[3];
    const float* W_in   = (const float*)d_in[4];
    const float* conv_w = (const float*)d_in[5];
    const float* conv_b = (const float*)d_in[6];
    const float* W_x    = (const float*)d_in[7];
    const float* W_dt   = (const float*)d_in[8];
    const float* b_dt   = (const float*)d_in[9];
    const float* A_log  = (const float*)d_in[10];
    const float* Dw     = (const float*)d_in[11];
    const float* W_out  = (const float*)d_in[12];
    float* out = (float*)d_out;
    float* ws  = (float*)d_ws;

    // Workspace layout (f32 units; total 37,224,448 < proven-safe 37,748,736):
    // [0,        1048576)  wout_b (2.10M bf16)            live: all
    // [1048576,  3145728)  win_b  (4.19M bf16)            live: G2
    // [3145728,  5242880)  xh_b   (4.19M bf16)            live: G1
    // [5242880,  5767168)  whf_b  (1.05M bf16)            live: G1
    // [5767168,  7864320)  m_b    (4.19M bf16)            live: G1->G2
    //   overlays after G2: part@3145728(3.15M f), xdbl@6291456(0.39M f),
    //   then after reduce: hloc@3145728, Pp@3670016, h0@4194304 (.52M f each)
    // [7864320, 16252928)  x_in fp32 (8.39M)  -> dt fp32 after conv
    // [16252928,24641536)  z    fp32 (8.39M)
    // [24641536,33030144)  xc   fp32 (8.39M)
    // [33030144,37224448)  yb   (8.39M bf16)
    __hip_bfloat16* wout_b = (__hip_bfloat16*)(ws);
    __hip_bfloat16* win_b  = (__hip_bfloat16*)(ws + 1048576);
    __hip_bfloat16* xh_b   = (__hip_bfloat16*)(ws + 3145728);
    __hip_bfloat16* whf_b  = (__hip_bfloat16*)(ws + 5242880);
    __hip_bfloat16* m_b    = (__hip_bfloat16*)(ws + 5767168);
    float* part = ws + 3145728;
    float* xdbl = ws + 6291456;
    float* hloc = ws + 3145728;
    float* Pp   = ws + 3670016;
    float* h0   = ws + 4194304;
    float* x_in = ws + 7864320;
    float* dt   = ws + 7864320;
    float* zp   = ws + 16252928;
    float* xc   = ws + 24641536;
    __hip_bfloat16* yb = (__hip_bfloat16*)(ws + 33030144);

    const int M = MROWS;

    // 0. pre-convert static operands to bf16
    cvt_bf16<<<2048, 256, 0, stream>>>(W_out, wout_b);   // 2,097,152
    cvt_bf16<<<4096, 256, 0, stream>>>(W_in,  win_b);    // 4,194,304
    cvt_bf16<<<4096, 256, 0, stream>>>(x_h,   xh_b);     // 4,194,304
    cvt_bf16<<<1024, 256, 0, stream>>>(W_hf,  whf_b);    // 1,048,576

    // 1. m_b = bf16( x_f * sigmoid(x_h @ W_hf^T + b_hf) )
    mfma_gemm<1><<<dim3(DMODEL / 128, M / 128), 256, 0, stream>>>(
        xh_b, DMODEL, whf_b, DMODEL, DMODEL,
        nullptr, DMODEL, m_b, nullptr, b_hf, x_f, DMODEL);

    // 2. [x_in | z] = m @ W_in^T  (split planes, fp32)
    mfma_gemm<2><<<dim3(4096 / 128, M / 128), 256, 0, stream>>>(
        m_b, DMODEL, win_b, DMODEL, DMODEL,
        x_in, 2048, nullptr, zp, nullptr, nullptr, 0);

    // 3. xc = silu(causal_conv4(x_in) + conv_b)
    conv_silu_kernel<<<(M * DINNER) / 256, 256, 0, stream>>>(x_in, conv_w, conv_b, xc);

    // 4. x_dbl = xc @ W_x^T  (fp32 split-K)
    gemm_tiled<0><<<dim3(1, M / 128, 8), 256, 0, stream>>>(
        xc, DINNER, W_x, DINNER, part, NDBL, M, NDBL, DINNER,
        nullptr, nullptr, 0, 256);
    reduce_splitk<<<(M * NDBL + 255) / 256, 256, 0, stream>>>(
        part, xdbl, M * NDBL, 8, (size_t)M * NDBL);

    // 5. dt = softplus(x_dbl[:, :64] @ W_dt^T + b_dt)  (fp32; overwrites x_in)
    gemm_tiled<2><<<dim3(DINNER / 128, M / 128, 1), 256, 0, stream>>>(
        xdbl, NDBL, W_dt, DTRANK, dt, DINNER, M, DINNER, DTRANK,
        b_dt, nullptr, 0, DTRANK);

    // 6. chunked scan; pass C writes bf16 y
    scan_pass_a<<<dim3(DINNER / 16, NCHUNK - 1, BATCH), 256, 0, stream>>>(
        dt, xc, xdbl, A_log, hloc, Pp);
    scan_pass_b<<<(BATCH * DINNER * DSTATE) / 256, 256, 0, stream>>>(hloc, Pp, h0);
    scan_pass_c<<<dim3(DINNER / 16, NCHUNK, BATCH), 256, 0, stream>>>(
        dt, xc, xdbl, zp, yb, A_log, Dw, h0);

    // 7. out = y @ W_out^T
    mfma_gemm<0><<<dim3(DMODEL / 128, M / 128), 256, 0, stream>>>(
        yb, DINNER, wout_b, DINNER, DINNER,
        out, DMODEL, nullptr, nullptr, nullptr, nullptr, 0);
}

// Round 6
// 327.527 us; speedup vs baseline: 7.9410x; 1.1887x over previous
//
#include <hip/hip_runtime.h>
#include <hip/hip_bf16.h>
#include <math.h>

#define L_SEQ  2048
#define BATCH  2
#define DMODEL 1024
#define DINNER 2048
#define DSTATE 16
#define NCHUNK 32
#define LCH    (L_SEQ / NCHUNK)  // 64

typedef __attribute__((ext_vector_type(8))) short bf16x8;
typedef __attribute__((ext_vector_type(4))) float f32x4;

__device__ __forceinline__ unsigned short f2bu(float x) {
    __hip_bfloat16 h = __float2bfloat16(x);
    return __builtin_bit_cast(unsigned short, h);
}
// v_exp_f32: D = 2^S0 (hardware exp2)
__device__ __forceinline__ float fast_exp2(float x) {
    float r; asm("v_exp_f32 %0, %1" : "=v"(r) : "v"(x)); return r;
}
#define LOG2E 1.44269504088896f

// ---------------------------------------------------------------------------
// fp32 -> bf16 conversion (n multiple of 1024).
// ---------------------------------------------------------------------------
__global__ __launch_bounds__(256) void cvt_bf16(
    const float* __restrict__ s, __hip_bfloat16* __restrict__ d)
{
    const int i = (blockIdx.x * 256 + threadIdx.x) * 4;
    const float4 v = *reinterpret_cast<const float4*>(&s[i]);
    ushort4 u;
    u.x = f2bu(v.x); u.y = f2bu(v.y); u.z = f2bu(v.z); u.w = f2bu(v.w);
    *reinterpret_cast<ushort4*>(&d[i]) = u;
}

// W_x (96x2048) -> bf16 padded to 128x2048 (rows 96..127 zero). grid 256.
__global__ __launch_bounds__(256) void cvt_pad_wx(
    const float* __restrict__ s, __hip_bfloat16* __restrict__ d)
{
    const int i = (blockIdx.x * 256 + threadIdx.x) * 4;   // over 128*2048
    const int r = i >> 11;
    ushort4 u = {0, 0, 0, 0};
    if (r < 96) {
        const float4 v = *reinterpret_cast<const float4*>(&s[i]);
        u.x = f2bu(v.x); u.y = f2bu(v.y); u.z = f2bu(v.z); u.w = f2bu(v.w);
    }
    *reinterpret_cast<ushort4*>(&d[i]) = u;
}

// ---------------------------------------------------------------------------
// MFMA bf16 GEMM: C[M,N] = epi(A[M,K] @ Bw[N,K]^T), 128x128 tile, BK=32,
// 4 waves (2x2), 16x16x32 MFMA. Split-K via gridDim.z (slice size ksz,
// output slice stride gridDim.y*128*ldc).
// EPI: 0 fp32 C; 1 bf16 C = sigmoid(acc+bias)*mul; 2 split fp32 planes
//      (col<2048 -> Cf, else C2, both stride 2048); 3 fp32 softplus(acc+bias).
// ---------------------------------------------------------------------------
template <int EPI>
__global__ __launch_bounds__(256) void mfma_gemm(
    const __hip_bfloat16* __restrict__ A, int lda,
    const __hip_bfloat16* __restrict__ Bw, int ldb,
    int ksz,
    float* __restrict__ Cf, int ldc,
    __hip_bfloat16* __restrict__ Cb,
    float* __restrict__ C2,
    const float* __restrict__ bias,
    const float* __restrict__ mul, int ldmul)
{
    __shared__ unsigned short As[128 * 32];
    __shared__ unsigned short Bs[128 * 32];
    const int tid = threadIdx.x;
    const int row0 = blockIdx.y * 128;
    const int col0 = blockIdx.x * 128;
    const int wid = tid >> 6, lane = tid & 63;
    const int wr = wid >> 1, wc = wid & 1;
    const int fr = lane & 15, fq = lane >> 4;
    const int kz0 = blockIdx.z * ksz;

    f32x4 acc[4][4];
#pragma unroll
    for (int i = 0; i < 4; i++)
#pragma unroll
        for (int j = 0; j < 4; j++) acc[i][j] = (f32x4){0.f, 0.f, 0.f, 0.f};

    const int i0 = tid, i1 = tid + 256;
    const size_t ga0 = (size_t)(row0 + (i0 >> 2)) * lda + (i0 & 3) * 8;
    const size_t ga1 = (size_t)(row0 + (i1 >> 2)) * lda + (i1 & 3) * 8;
    const size_t gb0 = (size_t)(col0 + (i0 >> 2)) * ldb + (i0 & 3) * 8;
    const size_t gb1 = (size_t)(col0 + (i1 >> 2)) * ldb + (i1 & 3) * 8;

    for (int kt = kz0; kt < kz0 + ksz; kt += 32) {
#if __has_builtin(__builtin_amdgcn_global_load_lds)
        __syncthreads();
        __builtin_amdgcn_global_load_lds(
            (const __attribute__((address_space(1))) unsigned int*)(A + ga0 + kt),
            (__attribute__((address_space(3))) unsigned int*)&As[i0 * 8], 16, 0, 0);
        __builtin_amdgcn_global_load_lds(
            (const __attribute__((address_space(1))) unsigned int*)(A + ga1 + kt),
            (__attribute__((address_space(3))) unsigned int*)&As[i1 * 8], 16, 0, 0);
        __builtin_amdgcn_global_load_lds(
            (const __attribute__((address_space(1))) unsigned int*)(Bw + gb0 + kt),
            (__attribute__((address_space(3))) unsigned int*)&Bs[i0 * 8], 16, 0, 0);
        __builtin_amdgcn_global_load_lds(
            (const __attribute__((address_space(1))) unsigned int*)(Bw + gb1 + kt),
            (__attribute__((address_space(3))) unsigned int*)&Bs[i1 * 8], 16, 0, 0);
        __syncthreads();
#else
        const uint4 va0 = *reinterpret_cast<const uint4*>(A + ga0 + kt);
        const uint4 va1 = *reinterpret_cast<const uint4*>(A + ga1 + kt);
        const uint4 vb0 = *reinterpret_cast<const uint4*>(Bw + gb0 + kt);
        const uint4 vb1 = *reinterpret_cast<const uint4*>(Bw + gb1 + kt);
        __syncthreads();
        *reinterpret_cast<uint4*>(&As[i0 * 8]) = va0;
        *reinterpret_cast<uint4*>(&As[i1 * 8]) = va1;
        *reinterpret_cast<uint4*>(&Bs[i0 * 8]) = vb0;
        *reinterpret_cast<uint4*>(&Bs[i1 * 8]) = vb1;
        __syncthreads();
#endif
        bf16x8 af[4], bf[4];
#pragma unroll
        for (int rb = 0; rb < 4; rb++)
            af[rb] = *reinterpret_cast<const bf16x8*>(
                &As[(wr * 64 + rb * 16 + fr) * 32 + fq * 8]);
#pragma unroll
        for (int cb = 0; cb < 4; cb++)
            bf[cb] = *reinterpret_cast<const bf16x8*>(
                &Bs[(wc * 64 + cb * 16 + fr) * 32 + fq * 8]);
#pragma unroll
        for (int rb = 0; rb < 4; rb++)
#pragma unroll
            for (int cb = 0; cb < 4; cb++)
                acc[rb][cb] = __builtin_amdgcn_mfma_f32_16x16x32_bf16(
                    af[rb], bf[cb], acc[rb][cb], 0, 0, 0);
    }

    // C/D layout: col = lane&15, row = (lane>>4)*4 + reg
    float* Cz = Cf;
    if (EPI == 0)
        Cz = Cf + (size_t)blockIdx.z * (size_t)(gridDim.y * 128) * ldc;
    const int r0 = row0 + wr * 64, c0 = col0 + wc * 64;
#pragma unroll
    for (int rb = 0; rb < 4; rb++)
#pragma unroll
        for (int cb = 0; cb < 4; cb++) {
            const int col = c0 + cb * 16 + fr;
#pragma unroll
            for (int j = 0; j < 4; j++) {
                const int row = r0 + rb * 16 + fq * 4 + j;
                float v = acc[rb][cb][j];
                if (EPI == 0) {
                    Cz[(size_t)row * ldc + col] = v;
                } else if (EPI == 1) {
                    v = 1.f / (1.f + __expf(-(v + bias[col])));
                    v *= mul[(size_t)row * ldmul + col];
                    Cb[(size_t)row * ldc + col] = __float2bfloat16(v);
                } else if (EPI == 2) {
                    if (col0 < 2048) Cf[(size_t)row * 2048 + col] = v;
                    else             C2[(size_t)row * 2048 + col - 2048] = v;
                } else {
                    v += bias[col];
                    v = (v > 20.f) ? v : log1pf(__expf(v));
                    Cf[(size_t)row * ldc + col] = v;
                }
            }
        }
}

// Split-K reduce for x_dbl (128-wide padded), also emits bf16 dt_r (cols<64).
__global__ __launch_bounds__(256) void reduce_xdbl(
    const float* __restrict__ part, float* __restrict__ xdbl,
    __hip_bfloat16* __restrict__ dtr)
{
    const int i = blockIdx.x * 256 + threadIdx.x;   // 4096*128
    float s = 0.f;
#pragma unroll
    for (int j = 0; j < 8; j++) s += part[(size_t)j * 524288 + i];
    xdbl[i] = s;
    const int col = i & 127;
    if (col < 64) dtr[((i >> 7) << 6) + col] = __float2bfloat16(s);
}

// Depthwise causal conv (width 4) + bias + SiLU -> bf16.
__global__ __launch_bounds__(256) void conv_silu_kernel(
    const float* __restrict__ x_in, const float* __restrict__ cw,
    const float* __restrict__ cb, __hip_bfloat16* __restrict__ xcb)
{
    int gid = blockIdx.x * 256 + threadIdx.x;   // 4096 * 2048 threads
    int e = gid & (DINNER - 1);
    int row = gid >> 11;
    int t = row & (L_SEQ - 1);
    float s = cb[e];
#pragma unroll
    for (int j = 0; j < 4; j++) {
        int tt = t - 3 + j;
        if (tt >= 0)
            s = fmaf(cw[e * 4 + j], x_in[(size_t)(row - 3 + j) * 2048 + e], s);
    }
    xcb[(size_t)row * 2048 + e] = __float2bfloat16(s / (1.f + __expf(-s)));
}

// ---------------------------------------------------------------------------
// Chunked selective scan, lane-owns-channel layout: each lane keeps h[16]
// (all states of one channel) in VGPRs. dt/xc/z are per-lane coalesced global
// scalars; B/C staged once per chunk in a 4KB LDS tile (broadcast b128 reads).
// NCHUNK=32, LCH=64. Block = 256 channels; grid (8, chunks, B).
// ---------------------------------------------------------------------------
__global__ __launch_bounds__(256) void scan_pass_a(
    const float* __restrict__ dtp, const __hip_bfloat16* __restrict__ xcb,
    const float* __restrict__ xdbl, const float* __restrict__ A_log,
    float* __restrict__ hloc, float* __restrict__ Pp)
{
    __shared__ float sB[LCH][16];
    const int tid = threadIdx.x;
    const int e = (blockIdx.x << 8) + tid;
    const int chunk = blockIdx.y;             // 0..NCHUNK-2
    const int b = blockIdx.z;
    const int t0 = chunk * LCH;

    {   // stage B tile: 64 rows x 16 s (256 float4 loads)
        const int r = tid >> 2, sl = tid & 3;
        *(float4*)&sB[r][sl * 4] =
            *(const float4*)&xdbl[(size_t)(b * L_SEQ + t0 + r) * 128 + 64 + sl * 4];
    }
    float av[16];
#pragma unroll
    for (int sq = 0; sq < 4; sq++) {
        const float4 al = *(const float4*)&A_log[e * 16 + sq * 4];
#pragma unroll
        for (int j = 0; j < 4; j++)
            av[sq * 4 + j] = -fast_exp2(((const float*)&al)[j] * LOG2E);
    }
    float h[16];
#pragma unroll
    for (int s = 0; s < 16; s++) h[s] = 0.f;
    float sdt = 0.f;
    __syncthreads();

    const size_t rb = (size_t)(b * L_SEQ + t0) * 2048 + e;
    float dtv_n = dtp[rb];
    float xv_n = __bfloat162float(xcb[rb]);
    for (int t = 0; t < LCH; t++) {
        const float dtv = dtv_n, xv = xv_n;
        if (t + 1 < LCH) {
            dtv_n = dtp[rb + (size_t)(t + 1) * 2048];
            xv_n = __bfloat162float(xcb[rb + (size_t)(t + 1) * 2048]);
        }
        sdt += dtv;
        const float dtx = dtv * xv;
        const float dl2 = dtv * LOG2E;
#pragma unroll
        for (int sq = 0; sq < 4; sq++) {
            const float4 B4 = *(const float4*)&sB[t][sq * 4];
#pragma unroll
            for (int j = 0; j < 4; j++) {
                const int s = sq * 4 + j;
                const float Bv = ((const float*)&B4)[j];
                h[s] = fmaf(fast_exp2(dl2 * av[s]), h[s], Bv * dtx);
            }
        }
    }
    const size_t o = (((size_t)chunk * BATCH + b) * 2048 + e) * 16;
#pragma unroll
    for (int sq = 0; sq < 4; sq++) {
        *(float4*)&hloc[o + sq * 4] =
            make_float4(h[sq * 4], h[sq * 4 + 1], h[sq * 4 + 2], h[sq * 4 + 3]);
        *(float4*)&Pp[o + sq * 4] = make_float4(
            fast_exp2(av[sq * 4] * sdt * LOG2E),
            fast_exp2(av[sq * 4 + 1] * sdt * LOG2E),
            fast_exp2(av[sq * 4 + 2] * sdt * LOG2E),
            fast_exp2(av[sq * 4 + 3] * sdt * LOG2E));
    }
}

__global__ __launch_bounds__(256) void scan_pass_b(
    const float* __restrict__ hloc, const float* __restrict__ Pp,
    float* __restrict__ h0)
{
    const int idx = blockIdx.x * 256 + threadIdx.x;   // 65536
    float h = 0.f;
    h0[idx] = 0.f;
    for (int c = 0; c < NCHUNK - 1; c++) {
        h = fmaf(Pp[(size_t)c * 65536 + idx], h, hloc[(size_t)c * 65536 + idx]);
        h0[(size_t)(c + 1) * 65536 + idx] = h;
    }
}

__global__ __launch_bounds__(256) void scan_pass_c(
    const float* __restrict__ dtp, const __hip_bfloat16* __restrict__ xcb,
    const float* __restrict__ xdbl, const float* __restrict__ zp,
    const float* __restrict__ A_log, const float* __restrict__ Dw,
    const float* __restrict__ h0, __hip_bfloat16* __restrict__ yb)
{
    __shared__ float sB[LCH][16];
    __shared__ float sC[LCH][16];
    const int tid = threadIdx.x;
    const int e = (blockIdx.x << 8) + tid;
    const int chunk = blockIdx.y;
    const int b = blockIdx.z;
    const int t0 = chunk * LCH;

    {
        const int r = tid >> 2, sl = tid & 3;
        const size_t base = (size_t)(b * L_SEQ + t0 + r) * 128;
        *(float4*)&sB[r][sl * 4] = *(const float4*)&xdbl[base + 64 + sl * 4];
        *(float4*)&sC[r][sl * 4] = *(const float4*)&xdbl[base + 80 + sl * 4];
    }
    float av[16];
#pragma unroll
    for (int sq = 0; sq < 4; sq++) {
        const float4 al = *(const float4*)&A_log[e * 16 + sq * 4];
#pragma unroll
        for (int j = 0; j < 4; j++)
            av[sq * 4 + j] = -fast_exp2(((const float*)&al)[j] * LOG2E);
    }
    const float De = Dw[e];
    float h[16];
    const size_t o = (((size_t)chunk * BATCH + b) * 2048 + e) * 16;
#pragma unroll
    for (int sq = 0; sq < 4; sq++) {
        const float4 hv = *(const float4*)&h0[o + sq * 4];
        h[sq * 4] = hv.x; h[sq * 4 + 1] = hv.y;
        h[sq * 4 + 2] = hv.z; h[sq * 4 + 3] = hv.w;
    }
    __syncthreads();

    const size_t rb = (size_t)(b * L_SEQ + t0) * 2048 + e;
    float dtv_n = dtp[rb];
    float xv_n = __bfloat162float(xcb[rb]);
    float zv_n = zp[rb];
    for (int t = 0; t < LCH; t++) {
        const float dtv = dtv_n, xv = xv_n, zv = zv_n;
        if (t + 1 < LCH) {
            dtv_n = dtp[rb + (size_t)(t + 1) * 2048];
            xv_n = __bfloat162float(xcb[rb + (size_t)(t + 1) * 2048]);
            zv_n = zp[rb + (size_t)(t + 1) * 2048];
        }
        const float dtx = dtv * xv;
        const float dl2 = dtv * LOG2E;
        float yp0 = 0.f, yp1 = 0.f, yp2 = 0.f, yp3 = 0.f;
#pragma unroll
        for (int sq = 0; sq < 4; sq++) {
            const float4 B4 = *(const float4*)&sB[t][sq * 4];
            const float4 C4 = *(const float4*)&sC[t][sq * 4];
#pragma unroll
            for (int j = 0; j < 4; j++) {
                const int s = sq * 4 + j;
                const float Bv = ((const float*)&B4)[j];
                const float Cv = ((const float*)&C4)[j];
                h[s] = fmaf(fast_exp2(dl2 * av[s]), h[s], Bv * dtx);
                if (sq == 0) yp0 = fmaf(h[s], Cv, yp0);
                else if (sq == 1) yp1 = fmaf(h[s], Cv, yp1);
                else if (sq == 2) yp2 = fmaf(h[s], Cv, yp2);
                else yp3 = fmaf(h[s], Cv, yp3);
            }
        }
        float yv = (yp0 + yp1) + (yp2 + yp3);
        yv = fmaf(De, xv, yv);
        const float sig = 1.f / (1.f + __expf(-zv));
        yb[rb + (size_t)t * 2048] = __float2bfloat16(yv * zv * sig);
    }
}

extern "C" void kernel_launch(void* const* d_in, const int* in_sizes, int n_in,
                              void* d_out, int out_size, void* d_ws, size_t ws_size,
                              hipStream_t stream)
{
    const float* x_f    = (const float*)d_in[0];
    const float* x_h    = (const float*)d_in[1];
    const float* W_hf   = (const float*)d_in[2];
    const float* b_hf   = (const float*)d_in[3];
    const float* W_in   = (const float*)d_in[4];
    const float* conv_w = (const float*)d_in[5];
    const float* conv_b = (const float*)d_in[6];
    const float* W_x    = (const float*)d_in[7];
    const float* W_dt   = (const float*)d_in[8];
    const float* b_dt   = (const float*)d_in[9];
    const float* A_log  = (const float*)d_in[10];
    const float* Dw     = (const float*)d_in[11];
    const float* W_out  = (const float*)d_in[12];
    float* out = (float*)d_out;
    float* ws  = (float*)d_ws;

    // Workspace (f32 units; total 37,552,128 f = 150.2MB <= proven 151MB):
    // [0,1048576)        wout_b (bf16, live all)
    // [1048576,5242880)  win_b+xh_b -> part (split-K partials) after G2
    // [5242880,5767168)  whf_b -> xdbl fp32 (4096x128) after G1
    // [5767168,7864320)  m_b -> hloc after G2
    // [7864320,7995392)  wx_b (128x2048 bf16, zero-padded)
    // [7995392,8060928)  wdt_b
    // [8060928,8192000)  dtr_b (4096x64 bf16)
    // [8192000,10289152) Pp
    // [10289152,12386304) h0
    // [12386304,16580608) xc_b (4096x2048 bf16)
    // [16580608,24969216) x_in -> dt fp32
    // [24969216,33357824) z fp32
    // [33357824,37552128) yb (bf16)
    __hip_bfloat16* wout_b = (__hip_bfloat16*)(ws);
    __hip_bfloat16* win_b  = (__hip_bfloat16*)(ws + 1048576);
    __hip_bfloat16* xh_b   = (__hip_bfloat16*)(ws + 3145728);
    float*          part   = ws + 1048576;
    __hip_bfloat16* whf_b  = (__hip_bfloat16*)(ws + 5242880);
    float*          xdbl   = ws + 5242880;
    __hip_bfloat16* m_b    = (__hip_bfloat16*)(ws + 5767168);
    float*          hloc   = ws + 5767168;
    __hip_bfloat16* wx_b   = (__hip_bfloat16*)(ws + 7864320);
    __hip_bfloat16* wdt_b  = (__hip_bfloat16*)(ws + 7995392);
    __hip_bfloat16* dtr_b  = (__hip_bfloat16*)(ws + 8060928);
    float*          Pp     = ws + 8192000;
    float*          h0     = ws + 10289152;
    __hip_bfloat16* xc_b   = (__hip_bfloat16*)(ws + 12386304);
    float*          x_in   = ws + 16580608;
    float*          dtp    = ws + 16580608;
    float*          zp     = ws + 24969216;
    __hip_bfloat16* yb     = (__hip_bfloat16*)(ws + 33357824);

    // 0. pre-convert static operands to bf16
    cvt_bf16<<<2048, 256, 0, stream>>>(W_out, wout_b);
    cvt_bf16<<<4096, 256, 0, stream>>>(W_in,  win_b);
    cvt_bf16<<<4096, 256, 0, stream>>>(x_h,   xh_b);
    cvt_bf16<<<1024, 256, 0, stream>>>(W_hf,  whf_b);
    cvt_pad_wx<<<256, 256, 0, stream>>>(W_x, wx_b);
    cvt_bf16<<<128, 256, 0, stream>>>(W_dt, wdt_b);

    // 1. m_b = bf16( x_f * sigmoid(x_h @ W_hf^T + b_hf) )
    mfma_gemm<1><<<dim3(8, 32, 1), 256, 0, stream>>>(
        xh_b, DMODEL, whf_b, DMODEL, DMODEL,
        nullptr, DMODEL, m_b, nullptr, b_hf, x_f, DMODEL);

    // 2. [x_in | z] = m @ W_in^T  (split fp32 planes)
    mfma_gemm<2><<<dim3(32, 32, 1), 256, 0, stream>>>(
        m_b, DMODEL, win_b, DMODEL, DMODEL,
        x_in, 2048, nullptr, zp, nullptr, nullptr, 0);

    // 3. xc_b = bf16( silu(causal_conv4(x_in) + conv_b) )  (4096*2048/256 blocks)
    conv_silu_kernel<<<32768, 256, 0, stream>>>(
        x_in, conv_w, conv_b, xc_b);

    // 4. x_dbl = xc @ W_x^T (padded N=128, MFMA split-K 8) + reduce
    mfma_gemm<0><<<dim3(1, 32, 8), 256, 0, stream>>>(
        xc_b, DINNER, wx_b, DINNER, 256,
        part, 128, nullptr, nullptr, nullptr, nullptr, 0);
    reduce_xdbl<<<2048, 256, 0, stream>>>(part, xdbl, dtr_b);

    // 5. dt = softplus(dt_r @ W_dt^T + b_dt)
    mfma_gemm<3><<<dim3(16, 32, 1), 256, 0, stream>>>(
        dtr_b, 64, wdt_b, 64, 64,
        dtp, 2048, nullptr, nullptr, b_dt, nullptr, 0);

    // 6. chunked scan (lane-owns-channel)
    scan_pass_a<<<dim3(8, NCHUNK - 1, BATCH), 256, 0, stream>>>(
        dtp, xc_b, xdbl, A_log, hloc, Pp);
    scan_pass_b<<<256, 256, 0, stream>>>(hloc, Pp, h0);
    scan_pass_c<<<dim3(8, NCHUNK, BATCH), 256, 0, stream>>>(
        dtp, xc_b, xdbl, zp, A_log, Dw, h0, yb);

    // 7. out = y @ W_out^T
    mfma_gemm<0><<<dim3(8, 32, 1), 256, 0, stream>>>(
        yb, DINNER, wout_b, DINNER, DINNER,
        out, DMODEL, nullptr, nullptr, nullptr, nullptr, 0);
}

// Round 9
// 314.933 us; speedup vs baseline: 8.2586x; 1.0400x over previous
//
#include <hip/hip_runtime.h>
#include <hip/hip_bf16.h>
#include <math.h>

#define L_SEQ  2048
#define BATCH  2
#define DMODEL 1024
#define DINNER 2048
#define DSTATE 16
#define NCHUNK 32
#define LCH    (L_SEQ / NCHUNK)  // 64

typedef __attribute__((ext_vector_type(8))) short bf16x8;
typedef __attribute__((ext_vector_type(4))) float f32x4;

__device__ __forceinline__ unsigned short f2bu(float x) {
    __hip_bfloat16 h = __float2bfloat16(x);
    return __builtin_bit_cast(unsigned short, h);
}
// v_exp_f32: D = 2^S0 (hardware exp2)
__device__ __forceinline__ float fast_exp2(float x) {
    float r; asm("v_exp_f32 %0, %1" : "=v"(r) : "v"(x)); return r;
}
#define LOG2E 1.44269504088896f

// ---------------------------------------------------------------------------
// fp32 -> bf16 conversion (n multiple of 1024).
// ---------------------------------------------------------------------------
__global__ __launch_bounds__(256) void cvt_bf16(
    const float* __restrict__ s, __hip_bfloat16* __restrict__ d)
{
    const int i = (blockIdx.x * 256 + threadIdx.x) * 4;
    const float4 v = *reinterpret_cast<const float4*>(&s[i]);
    ushort4 u;
    u.x = f2bu(v.x); u.y = f2bu(v.y); u.z = f2bu(v.z); u.w = f2bu(v.w);
    *reinterpret_cast<ushort4*>(&d[i]) = u;
}

// W_x (96x2048) -> bf16 padded to 128x2048 (rows 96..127 zero). grid 256.
__global__ __launch_bounds__(256) void cvt_pad_wx(
    const float* __restrict__ s, __hip_bfloat16* __restrict__ d)
{
    const int i = (blockIdx.x * 256 + threadIdx.x) * 4;   // over 128*2048
    const int r = i >> 11;
    ushort4 u = {0, 0, 0, 0};
    if (r < 96) {
        const float4 v = *reinterpret_cast<const float4*>(&s[i]);
        u.x = f2bu(v.x); u.y = f2bu(v.y); u.z = f2bu(v.z); u.w = f2bu(v.w);
    }
    *reinterpret_cast<ushort4*>(&d[i]) = u;
}

// ---------------------------------------------------------------------------
// MFMA bf16 GEMM: C[M,N] = epi(A[M,K] @ Bw[N,K]^T), 128x128 tile, BK=32,
// 4 waves (2x2), 16x16x32 MFMA. Double-buffered LDS, prefetch-early:
// iteration k issues global_load_lds for tile k+1 into buf^1, computes tile k
// from buf, then ONE __syncthreads() (drains vmcnt AFTER compute -> overlap;
// full-drain semantics make the buffer swap race-free).
// Split-K via gridDim.z (slice ksz, partial slice stride gridDim.y*128*ldc).
// EPI: 0 fp32 C; 1 bf16 C = sigmoid(acc+bias)*mul; 2 bf16 split planes
//      (col<2048 -> Cb, else Cb2, both stride 2048); 3 fp32 softplus(acc+bias).
// ---------------------------------------------------------------------------
template <int EPI>
__global__ __launch_bounds__(256) void mfma_gemm(
    const __hip_bfloat16* __restrict__ A, int lda,
    const __hip_bfloat16* __restrict__ Bw, int ldb,
    int ksz,
    float* __restrict__ Cf, int ldc,
    __hip_bfloat16* __restrict__ Cb,
    __hip_bfloat16* __restrict__ Cb2,
    const float* __restrict__ bias,
    const float* __restrict__ mul, int ldmul)
{
    __shared__ unsigned short As[2][128 * 32];
    __shared__ unsigned short Bs[2][128 * 32];
    const int tid = threadIdx.x;
    const int row0 = blockIdx.y * 128;
    const int col0 = blockIdx.x * 128;
    const int wid = tid >> 6, lane = tid & 63;
    const int wr = wid >> 1, wc = wid & 1;
    const int fr = lane & 15, fq = lane >> 4;
    const int kz0 = blockIdx.z * ksz;

    f32x4 acc[4][4];
#pragma unroll
    for (int i = 0; i < 4; i++)
#pragma unroll
        for (int j = 0; j < 4; j++) acc[i][j] = (f32x4){0.f, 0.f, 0.f, 0.f};

    const int i0 = tid, i1 = tid + 256;
    const size_t ga0 = (size_t)(row0 + (i0 >> 2)) * lda + (i0 & 3) * 8;
    const size_t ga1 = (size_t)(row0 + (i1 >> 2)) * lda + (i1 & 3) * 8;
    const size_t gb0 = (size_t)(col0 + (i0 >> 2)) * ldb + (i0 & 3) * 8;
    const size_t gb1 = (size_t)(col0 + (i1 >> 2)) * ldb + (i1 & 3) * 8;
    const int nk = ksz >> 5;

#if __has_builtin(__builtin_amdgcn_global_load_lds)
    auto STAGE = [&](int buf, int koff) {
        __builtin_amdgcn_global_load_lds(
            (const __attribute__((address_space(1))) unsigned int*)(A + ga0 + koff),
            (__attribute__((address_space(3))) unsigned int*)&As[buf][i0 * 8], 16, 0, 0);
        __builtin_amdgcn_global_load_lds(
            (const __attribute__((address_space(1))) unsigned int*)(A + ga1 + koff),
            (__attribute__((address_space(3))) unsigned int*)&As[buf][i1 * 8], 16, 0, 0);
        __builtin_amdgcn_global_load_lds(
            (const __attribute__((address_space(1))) unsigned int*)(Bw + gb0 + koff),
            (__attribute__((address_space(3))) unsigned int*)&Bs[buf][i0 * 8], 16, 0, 0);
        __builtin_amdgcn_global_load_lds(
            (const __attribute__((address_space(1))) unsigned int*)(Bw + gb1 + koff),
            (__attribute__((address_space(3))) unsigned int*)&Bs[buf][i1 * 8], 16, 0, 0);
    };
    STAGE(0, kz0);
    __syncthreads();   // tile 0 visible
    for (int kk = 0; kk < nk; kk++) {
        const int cur = kk & 1;
        if (kk + 1 < nk) STAGE(cur ^ 1, kz0 + (kk + 1) * 32);   // prefetch
        bf16x8 af[4], bq[4];
#pragma unroll
        for (int rb = 0; rb < 4; rb++)
            af[rb] = *reinterpret_cast<const bf16x8*>(
                &As[cur][(wr * 64 + rb * 16 + fr) * 32 + fq * 8]);
#pragma unroll
        for (int cb = 0; cb < 4; cb++)
            bq[cb] = *reinterpret_cast<const bf16x8*>(
                &Bs[cur][(wc * 64 + cb * 16 + fr) * 32 + fq * 8]);
#pragma unroll
        for (int rb = 0; rb < 4; rb++)
#pragma unroll
            for (int cb = 0; cb < 4; cb++)
                acc[rb][cb] = __builtin_amdgcn_mfma_f32_16x16x32_bf16(
                    af[rb], bq[cb], acc[rb][cb], 0, 0, 0);
        // single barrier: drains prefetch vmcnt AFTER compute (overlap) and
        // guarantees all reads of buf[cur] done before it is restaged.
        __syncthreads();
    }
#else
    for (int kk = 0; kk < nk; kk++) {
        const int koff = kz0 + kk * 32;
        const uint4 va0 = *reinterpret_cast<const uint4*>(A + ga0 + koff);
        const uint4 va1 = *reinterpret_cast<const uint4*>(A + ga1 + koff);
        const uint4 vb0 = *reinterpret_cast<const uint4*>(Bw + gb0 + koff);
        const uint4 vb1 = *reinterpret_cast<const uint4*>(Bw + gb1 + koff);
        __syncthreads();
        *reinterpret_cast<uint4*>(&As[0][i0 * 8]) = va0;
        *reinterpret_cast<uint4*>(&As[0][i1 * 8]) = va1;
        *reinterpret_cast<uint4*>(&Bs[0][i0 * 8]) = vb0;
        *reinterpret_cast<uint4*>(&Bs[0][i1 * 8]) = vb1;
        __syncthreads();
        bf16x8 af[4], bq[4];
#pragma unroll
        for (int rb = 0; rb < 4; rb++)
            af[rb] = *reinterpret_cast<const bf16x8*>(
                &As[0][(wr * 64 + rb * 16 + fr) * 32 + fq * 8]);
#pragma unroll
        for (int cb = 0; cb < 4; cb++)
            bq[cb] = *reinterpret_cast<const bf16x8*>(
                &Bs[0][(wc * 64 + cb * 16 + fr) * 32 + fq * 8]);
#pragma unroll
        for (int rb = 0; rb < 4; rb++)
#pragma unroll
            for (int cb = 0; cb < 4; cb++)
                acc[rb][cb] = __builtin_amdgcn_mfma_f32_16x16x32_bf16(
                    af[rb], bq[cb], acc[rb][cb], 0, 0, 0);
    }
#endif

    // C/D layout: col = lane&15, row = (lane>>4)*4 + reg
    float* Cz = Cf;
    if (EPI == 0)
        Cz = Cf + (size_t)blockIdx.z * (size_t)(gridDim.y * 128) * ldc;
    const int r0 = row0 + wr * 64, c0 = col0 + wc * 64;
#pragma unroll
    for (int rb = 0; rb < 4; rb++)
#pragma unroll
        for (int cb = 0; cb < 4; cb++) {
            const int col = c0 + cb * 16 + fr;
#pragma unroll
            for (int j = 0; j < 4; j++) {
                const int row = r0 + rb * 16 + fq * 4 + j;
                float v = acc[rb][cb][j];
                if (EPI == 0) {
                    Cz[(size_t)row * ldc + col] = v;
                } else if (EPI == 1) {
                    v = 1.f / (1.f + __expf(-(v + bias[col])));
                    v *= mul[(size_t)row * ldmul + col];
                    Cb[(size_t)row * ldc + col] = __float2bfloat16(v);
                } else if (EPI == 2) {
                    if (col0 < 2048) Cb[(size_t)row * 2048 + col] = __float2bfloat16(v);
                    else             Cb2[(size_t)row * 2048 + col - 2048] = __float2bfloat16(v);
                } else {
                    v += bias[col];
                    v = (v > 20.f) ? v : log1pf(__expf(v));
                    Cf[(size_t)row * ldc + col] = v;
                }
            }
        }
}

// Split-K reduce for x_dbl (128-wide padded), also emits bf16 dt_r (cols<64).
__global__ __launch_bounds__(256) void reduce_xdbl(
    const float* __restrict__ part, float* __restrict__ xdbl,
    __hip_bfloat16* __restrict__ dtr)
{
    const int i = blockIdx.x * 256 + threadIdx.x;   // 4096*128
    float s = 0.f;
#pragma unroll
    for (int j = 0; j < 4; j++) s += part[(size_t)j * 524288 + i];
    xdbl[i] = s;
    const int col = i & 127;
    if (col < 64) dtr[((i >> 7) << 6) + col] = __float2bfloat16(s);
}

// Depthwise causal conv (width 4) + bias + SiLU. bf16 in -> bf16 out.
__global__ __launch_bounds__(256) void conv_silu_kernel(
    const __hip_bfloat16* __restrict__ xin_b, const float* __restrict__ cw,
    const float* __restrict__ cb, __hip_bfloat16* __restrict__ xcb)
{
    int gid = blockIdx.x * 256 + threadIdx.x;   // 4096 * 2048 threads
    int e = gid & (DINNER - 1);
    int row = gid >> 11;
    int t = row & (L_SEQ - 1);
    float s = cb[e];
#pragma unroll
    for (int j = 0; j < 4; j++) {
        int tt = t - 3 + j;
        if (tt >= 0)
            s = fmaf(cw[e * 4 + j],
                     __bfloat162float(xin_b[(size_t)(row - 3 + j) * 2048 + e]), s);
    }
    xcb[(size_t)row * 2048 + e] = __float2bfloat16(s / (1.f + __expf(-s)));
}

// ---------------------------------------------------------------------------
// Chunked selective scan, lane-owns-channel layout: each lane keeps h[16]
// (all states of one channel) in VGPRs. dt/xc/z are per-lane coalesced global
// scalars; B/C staged once per chunk in a 4KB LDS tile (broadcast b128 reads).
// NCHUNK=32, LCH=64. Block = 256 channels; grid (8, chunks, B).
// hloc/Pp sized (NCHUNK-1)*B*DINNER*DSTATE, h0 sized NCHUNK*B*DINNER*DSTATE
// = 2,031,616 / 2,097,152 floats (R7/R8 undersized these at 524,288 -> the
// buffers aliased each other -> full-scale corruption; fixed here).
// ---------------------------------------------------------------------------
__global__ __launch_bounds__(256) void scan_pass_a(
    const float* __restrict__ dtp, const __hip_bfloat16* __restrict__ xcb,
    const float* __restrict__ xdbl, const float* __restrict__ A_log,
    float* __restrict__ hloc, float* __restrict__ Pp)
{
    __shared__ float sB[LCH][16];
    const int tid = threadIdx.x;
    const int e = (blockIdx.x << 8) + tid;
    const int chunk = blockIdx.y;             // 0..NCHUNK-2
    const int b = blockIdx.z;
    const int t0 = chunk * LCH;

    {   // stage B tile: 64 rows x 16 s (256 float4 loads)
        const int r = tid >> 2, sl = tid & 3;
        *(float4*)&sB[r][sl * 4] =
            *(const float4*)&xdbl[(size_t)(b * L_SEQ + t0 + r) * 128 + 64 + sl * 4];
    }
    float av[16];
#pragma unroll
    for (int sq = 0; sq < 4; sq++) {
        const float4 al = *(const float4*)&A_log[e * 16 + sq * 4];
#pragma unroll
        for (int j = 0; j < 4; j++)
            av[sq * 4 + j] = -fast_exp2(((const float*)&al)[j] * LOG2E);
    }
    float h[16];
#pragma unroll
    for (int s = 0; s < 16; s++) h[s] = 0.f;
    float sdt = 0.f;
    __syncthreads();

    const size_t rb = (size_t)(b * L_SEQ + t0) * 2048 + e;
    float dtv_n = dtp[rb];
    float xv_n = __bfloat162float(xcb[rb]);
    for (int t = 0; t < LCH; t++) {
        const float dtv = dtv_n, xv = xv_n;
        if (t + 1 < LCH) {
            dtv_n = dtp[rb + (size_t)(t + 1) * 2048];
            xv_n = __bfloat162float(xcb[rb + (size_t)(t + 1) * 2048]);
        }
        sdt += dtv;
        const float dtx = dtv * xv;
        const float dl2 = dtv * LOG2E;
#pragma unroll
        for (int sq = 0; sq < 4; sq++) {
            const float4 B4 = *(const float4*)&sB[t][sq * 4];
#pragma unroll
            for (int j = 0; j < 4; j++) {
                const int s = sq * 4 + j;
                const float Bv = ((const float*)&B4)[j];
                h[s] = fmaf(fast_exp2(dl2 * av[s]), h[s], Bv * dtx);
            }
        }
    }
    const size_t o = (((size_t)chunk * BATCH + b) * 2048 + e) * 16;
#pragma unroll
    for (int sq = 0; sq < 4; sq++) {
        *(float4*)&hloc[o + sq * 4] =
            make_float4(h[sq * 4], h[sq * 4 + 1], h[sq * 4 + 2], h[sq * 4 + 3]);
        *(float4*)&Pp[o + sq * 4] = make_float4(
            fast_exp2(av[sq * 4] * sdt * LOG2E),
            fast_exp2(av[sq * 4 + 1] * sdt * LOG2E),
            fast_exp2(av[sq * 4 + 2] * sdt * LOG2E),
            fast_exp2(av[sq * 4 + 3] * sdt * LOG2E));
    }
}

__global__ __launch_bounds__(256) void scan_pass_b(
    const float* __restrict__ hloc, const float* __restrict__ Pp,
    float* __restrict__ h0)
{
    const int idx = blockIdx.x * 256 + threadIdx.x;   // 65536
    float h = 0.f;
    h0[idx] = 0.f;
    for (int c = 0; c < NCHUNK - 1; c++) {
        h = fmaf(Pp[(size_t)c * 65536 + idx], h, hloc[(size_t)c * 65536 + idx]);
        h0[(size_t)(c + 1) * 65536 + idx] = h;
    }
}

__global__ __launch_bounds__(256) void scan_pass_c(
    const float* __restrict__ dtp, const __hip_bfloat16* __restrict__ xcb,
    const float* __restrict__ xdbl, const __hip_bfloat16* __restrict__ zb,
    const float* __restrict__ A_log, const float* __restrict__ Dw,
    const float* __restrict__ h0, __hip_bfloat16* __restrict__ yb)
{
    __shared__ float sB[LCH][16];
    __shared__ float sC[LCH][16];
    const int tid = threadIdx.x;
    const int e = (blockIdx.x << 8) + tid;
    const int chunk = blockIdx.y;
    const int b = blockIdx.z;
    const int t0 = chunk * LCH;

    {
        const int r = tid >> 2, sl = tid & 3;
        const size_t base = (size_t)(b * L_SEQ + t0 + r) * 128;
        *(float4*)&sB[r][sl * 4] = *(const float4*)&xdbl[base + 64 + sl * 4];
        *(float4*)&sC[r][sl * 4] = *(const float4*)&xdbl[base + 80 + sl * 4];
    }
    float av[16];
#pragma unroll
    for (int sq = 0; sq < 4; sq++) {
        const float4 al = *(const float4*)&A_log[e * 16 + sq * 4];
#pragma unroll
        for (int j = 0; j < 4; j++)
            av[sq * 4 + j] = -fast_exp2(((const float*)&al)[j] * LOG2E);
    }
    const float De = Dw[e];
    float h[16];
    const size_t o = (((size_t)chunk * BATCH + b) * 2048 + e) * 16;
#pragma unroll
    for (int sq = 0; sq < 4; sq++) {
        const float4 hv = *(const float4*)&h0[o + sq * 4];
        h[sq * 4] = hv.x; h[sq * 4 + 1] = hv.y;
        h[sq * 4 + 2] = hv.z; h[sq * 4 + 3] = hv.w;
    }
    __syncthreads();

    const size_t rb = (size_t)(b * L_SEQ + t0) * 2048 + e;
    float dtv_n = dtp[rb];
    float xv_n = __bfloat162float(xcb[rb]);
    float zv_n = __bfloat162float(zb[rb]);
    for (int t = 0; t < LCH; t++) {
        const float dtv = dtv_n, xv = xv_n, zv = zv_n;
        if (t + 1 < LCH) {
            dtv_n = dtp[rb + (size_t)(t + 1) * 2048];
            xv_n = __bfloat162float(xcb[rb + (size_t)(t + 1) * 2048]);
            zv_n = __bfloat162float(zb[rb + (size_t)(t + 1) * 2048]);
        }
        const float dtx = dtv * xv;
        const float dl2 = dtv * LOG2E;
        float yp0 = 0.f, yp1 = 0.f, yp2 = 0.f, yp3 = 0.f;
#pragma unroll
        for (int sq = 0; sq < 4; sq++) {
            const float4 B4 = *(const float4*)&sB[t][sq * 4];
            const float4 C4 = *(const float4*)&sC[t][sq * 4];
#pragma unroll
            for (int j = 0; j < 4; j++) {
                const int s = sq * 4 + j;
                const float Bv = ((const float*)&B4)[j];
                const float Cv = ((const float*)&C4)[j];
                h[s] = fmaf(fast_exp2(dl2 * av[s]), h[s], Bv * dtx);
                if (sq == 0) yp0 = fmaf(h[s], Cv, yp0);
                else if (sq == 1) yp1 = fmaf(h[s], Cv, yp1);
                else if (sq == 2) yp2 = fmaf(h[s], Cv, yp2);
                else yp3 = fmaf(h[s], Cv, yp3);
            }
        }
        float yv = (yp0 + yp1) + (yp2 + yp3);
        yv = fmaf(De, xv, yv);
        const float sig = 1.f / (1.f + __expf(-zv));
        yb[rb + (size_t)t * 2048] = __float2bfloat16(yv * zv * sig);
    }
}

extern "C" void kernel_launch(void* const* d_in, const int* in_sizes, int n_in,
                              void* d_out, int out_size, void* d_ws, size_t ws_size,
                              hipStream_t stream)
{
    const float* x_f    = (const float*)d_in[0];
    const float* x_h    = (const float*)d_in[1];
    const float* W_hf   = (const float*)d_in[2];
    const float* b_hf   = (const float*)d_in[3];
    const float* W_in   = (const float*)d_in[4];
    const float* conv_w = (const float*)d_in[5];
    const float* conv_b = (const float*)d_in[6];
    const float* W_x    = (const float*)d_in[7];
    const float* W_dt   = (const float*)d_in[8];
    const float* b_dt   = (const float*)d_in[9];
    const float* A_log  = (const float*)d_in[10];
    const float* Dw     = (const float*)d_in[11];
    const float* W_out  = (const float*)d_in[12];
    float* out = (float*)d_out;
    float* ws  = (float*)d_ws;

    // Workspace (f32 units; total 35,979,264 f = 143.9MB <= proven 151MB).
    // GEMM-phase buffers [1048576, 7864320) (win_b/xh_b/whf_b/m_b) are dead
    // after G2 and are overlaid by the scan-phase hloc/Pp/h0 (each correctly
    // sized; cvt re-writes the GEMM buffers at the start of every call):
    __hip_bfloat16* wout_b = (__hip_bfloat16*)(ws);              // 1,048,576 f
    __hip_bfloat16* win_b  = (__hip_bfloat16*)(ws + 1048576);    // 2,097,152 f
    __hip_bfloat16* xh_b   = (__hip_bfloat16*)(ws + 3145728);    // 2,097,152 f
    __hip_bfloat16* whf_b  = (__hip_bfloat16*)(ws + 5242880);    //   524,288 f
    __hip_bfloat16* m_b    = (__hip_bfloat16*)(ws + 5767168);    // 2,097,152 f
    float*          hloc   = ws + 1048576;   // 2,097,152 f (scan overlay)
    float*          Pp     = ws + 3145728;   // 2,097,152 f (scan overlay)
    float*          h0     = ws + 5242880;   // 2,097,152 f (scan overlay, ends 7,340,032)
    __hip_bfloat16* wx_b   = (__hip_bfloat16*)(ws + 7864320);    //   131,072 f
    __hip_bfloat16* wdt_b  = (__hip_bfloat16*)(ws + 7995392);    //    65,536 f
    __hip_bfloat16* dtr_b  = (__hip_bfloat16*)(ws + 8060928);    //   131,072 f
    float*          part   = ws + 8192000;                       // 2,097,152 f
    float*          xdbl   = ws + 10289152;                      //   524,288 f
    __hip_bfloat16* xin_b  = (__hip_bfloat16*)(ws + 10813440);   // 4,194,304 f
    __hip_bfloat16* z_b    = (__hip_bfloat16*)(ws + 15007744);   // 4,194,304 f
    __hip_bfloat16* xc_b   = (__hip_bfloat16*)(ws + 19202048);   // 4,194,304 f
    float*          dtp    = ws + 23396352;                      // 8,388,608 f
    __hip_bfloat16* yb     = (__hip_bfloat16*)(ws + 31784960);   // 4,194,304 f

    // 0. pre-convert static operands to bf16
    cvt_bf16<<<2048, 256, 0, stream>>>(W_out, wout_b);
    cvt_bf16<<<4096, 256, 0, stream>>>(W_in,  win_b);
    cvt_bf16<<<4096, 256, 0, stream>>>(x_h,   xh_b);
    cvt_bf16<<<1024, 256, 0, stream>>>(W_hf,  whf_b);
    cvt_pad_wx<<<256, 256, 0, stream>>>(W_x, wx_b);
    cvt_bf16<<<128, 256, 0, stream>>>(W_dt, wdt_b);

    // 1. m_b = bf16( x_f * sigmoid(x_h @ W_hf^T + b_hf) )
    mfma_gemm<1><<<dim3(8, 32, 1), 256, 0, stream>>>(
        xh_b, DMODEL, whf_b, DMODEL, DMODEL,
        nullptr, DMODEL, m_b, nullptr, b_hf, x_f, DMODEL);

    // 2. [x_in | z] = m @ W_in^T  (bf16 split planes)
    mfma_gemm<2><<<dim3(32, 32, 1), 256, 0, stream>>>(
        m_b, DMODEL, win_b, DMODEL, DMODEL,
        nullptr, 2048, xin_b, z_b, nullptr, nullptr, 0);

    // 3. xc_b = bf16( silu(causal_conv4(x_in) + conv_b) )
    conv_silu_kernel<<<32768, 256, 0, stream>>>(
        xin_b, conv_w, conv_b, xc_b);

    // 4. x_dbl = xc @ W_x^T (padded N=128, MFMA split-K 4) + reduce
    mfma_gemm<0><<<dim3(1, 32, 4), 256, 0, stream>>>(
        xc_b, DINNER, wx_b, DINNER, 512,
        part, 128, nullptr, nullptr, nullptr, nullptr, 0);
    reduce_xdbl<<<2048, 256, 0, stream>>>(part, xdbl, dtr_b);

    // 5. dt = softplus(dt_r @ W_dt^T + b_dt)
    mfma_gemm<3><<<dim3(16, 32, 1), 256, 0, stream>>>(
        dtr_b, 64, wdt_b, 64, 64,
        dtp, 2048, nullptr, nullptr, b_dt, nullptr, 0);

    // 6. chunked scan (lane-owns-channel; buffers correctly sized this round)
    scan_pass_a<<<dim3(8, NCHUNK - 1, BATCH), 256, 0, stream>>>(
        dtp, xc_b, xdbl, A_log, hloc, Pp);
    scan_pass_b<<<256, 256, 0, stream>>>(hloc, Pp, h0);
    scan_pass_c<<<dim3(8, NCHUNK, BATCH), 256, 0, stream>>>(
        dtp, xc_b, xdbl, z_b, A_log, Dw, h0, yb);

    // 7. out = y @ W_out^T
    mfma_gemm<0><<<dim3(8, 32, 1), 256, 0, stream>>>(
        yb, DINNER, wout_b, DINNER, DINNER,
        out, DMODEL, nullptr, nullptr, nullptr, nullptr, 0);
}

// Round 10
// 313.680 us; speedup vs baseline: 8.2916x; 1.0040x over previous
//
#include <hip/hip_runtime.h>
#include <hip/hip_bf16.h>
#include <math.h>

#define L_SEQ  2048
#define BATCH  2
#define DMODEL 1024
#define DINNER 2048
#define DSTATE 16
#define NCHUNK 32
#define LCH    (L_SEQ / NCHUNK)  // 64

typedef __attribute__((ext_vector_type(8))) short bf16x8;
typedef __attribute__((ext_vector_type(4))) float f32x4;

__device__ __forceinline__ unsigned short f2bu(float x) {
    __hip_bfloat16 h = __float2bfloat16(x);
    return __builtin_bit_cast(unsigned short, h);
}
// v_exp_f32: D = 2^S0 (hardware exp2)
__device__ __forceinline__ float fast_exp2(float x) {
    float r; asm("v_exp_f32 %0, %1" : "=v"(r) : "v"(x)); return r;
}
#define LOG2E 1.44269504088896f

// ---------------------------------------------------------------------------
// Fused fp32 -> bf16 conversion for all static operands (one launch).
// Segments (vec4 blocks of 256 thr): Wout 2048 | Win 4096 | xh 4096 |
// Whf 1024 | Wx-pad 256 | Wdt 128  => grid 11648.
// ---------------------------------------------------------------------------
__global__ __launch_bounds__(256) void cvt_all(
    const float* __restrict__ Wout, const float* __restrict__ Win,
    const float* __restrict__ xh,   const float* __restrict__ Whf,
    const float* __restrict__ Wx,   const float* __restrict__ Wdt,
    __hip_bfloat16* __restrict__ dWout, __hip_bfloat16* __restrict__ dWin,
    __hip_bfloat16* __restrict__ dxh,   __hip_bfloat16* __restrict__ dWhf,
    __hip_bfloat16* __restrict__ dWx,   __hip_bfloat16* __restrict__ dWdt)
{
    int bid = blockIdx.x;
    const float* s; __hip_bfloat16* d;
    if (bid < 2048)       { s = Wout; d = dWout; }
    else if (bid < 6144)  { s = Win;  d = dWin;  bid -= 2048; }
    else if (bid < 10240) { s = xh;   d = dxh;   bid -= 6144; }
    else if (bid < 11264) { s = Whf;  d = dWhf;  bid -= 10240; }
    else if (bid < 11520) {
        // W_x (96x2048) -> 128x2048, rows 96..127 zero
        bid -= 11264;
        const int i = (bid * 256 + threadIdx.x) * 4;
        const int r = i >> 11;
        ushort4 u = {0, 0, 0, 0};
        if (r < 96) {
            const float4 v = *reinterpret_cast<const float4*>(&Wx[i]);
            u.x = f2bu(v.x); u.y = f2bu(v.y); u.z = f2bu(v.z); u.w = f2bu(v.w);
        }
        *reinterpret_cast<ushort4*>(&dWx[i]) = u;
        return;
    }
    else                  { s = Wdt;  d = dWdt;  bid -= 11520; }
    const int i = (bid * 256 + threadIdx.x) * 4;
    const float4 v = *reinterpret_cast<const float4*>(&s[i]);
    ushort4 u;
    u.x = f2bu(v.x); u.y = f2bu(v.y); u.z = f2bu(v.z); u.w = f2bu(v.w);
    *reinterpret_cast<ushort4*>(&d[i]) = u;
}

// ---------------------------------------------------------------------------
// MFMA bf16 GEMM: C[M,N] = epi(A[M,K] @ Bw[N,K]^T), 128x128 tile, BK=32,
// 4 waves (2x2), 16x16x32 MFMA.
// 3-buffer / 2-deep pipeline with COUNTED vmcnt (T4): iter k stages tile k+2,
// computes tile k, then waits vmcnt(4) (own tile-k+1 loads retired, in-order)
// + raw s_barrier + sched_barrier(0). Loads get ~2 iterations to land instead
// of <1 (the __syncthreads full-drain that pinned R6/R9 at ~604 TF).
// Safety: every wave passed its own vmcnt before the barrier => buffer
// globally staged; buf (k+2)%3's previous readers finished before the barrier
// that ended iter k-1; sched_barrier(0) stops hoisting across s_barrier.
// Requires nk >= 2 (all call sites satisfy; smallest is G5 with nk=2).
// Split-K via gridDim.z (slice ksz, partial slice stride gridDim.y*128*ldc).
// EPI: 0 fp32 C; 1 bf16 C = sigmoid(acc+bias)*mul; 2 bf16 split planes
//      (col<2048 -> Cb, else Cb2, both stride 2048); 3 fp32 softplus(acc+bias).
// ---------------------------------------------------------------------------
template <int EPI>
__global__ __launch_bounds__(256) void mfma_gemm(
    const __hip_bfloat16* __restrict__ A, int lda,
    const __hip_bfloat16* __restrict__ Bw, int ldb,
    int ksz,
    float* __restrict__ Cf, int ldc,
    __hip_bfloat16* __restrict__ Cb,
    __hip_bfloat16* __restrict__ Cb2,
    const float* __restrict__ bias,
    const float* __restrict__ mul, int ldmul)
{
    __shared__ unsigned short As[3][128 * 32];
    __shared__ unsigned short Bs[3][128 * 32];
    const int tid = threadIdx.x;
    const int row0 = blockIdx.y * 128;
    const int col0 = blockIdx.x * 128;
    const int wid = tid >> 6, lane = tid & 63;
    const int wr = wid >> 1, wc = wid & 1;
    const int fr = lane & 15, fq = lane >> 4;
    const int kz0 = blockIdx.z * ksz;

    f32x4 acc[4][4];
#pragma unroll
    for (int i = 0; i < 4; i++)
#pragma unroll
        for (int j = 0; j < 4; j++) acc[i][j] = (f32x4){0.f, 0.f, 0.f, 0.f};

    const int i0 = tid, i1 = tid + 256;
    const size_t ga0 = (size_t)(row0 + (i0 >> 2)) * lda + (i0 & 3) * 8;
    const size_t ga1 = (size_t)(row0 + (i1 >> 2)) * lda + (i1 & 3) * 8;
    const size_t gb0 = (size_t)(col0 + (i0 >> 2)) * ldb + (i0 & 3) * 8;
    const size_t gb1 = (size_t)(col0 + (i1 >> 2)) * ldb + (i1 & 3) * 8;
    const int nk = ksz >> 5;

#if __has_builtin(__builtin_amdgcn_global_load_lds)
    auto STAGE = [&](int buf, int koff) {
        __builtin_amdgcn_global_load_lds(
            (const __attribute__((address_space(1))) unsigned int*)(A + ga0 + koff),
            (__attribute__((address_space(3))) unsigned int*)&As[buf][i0 * 8], 16, 0, 0);
        __builtin_amdgcn_global_load_lds(
            (const __attribute__((address_space(1))) unsigned int*)(A + ga1 + koff),
            (__attribute__((address_space(3))) unsigned int*)&As[buf][i1 * 8], 16, 0, 0);
        __builtin_amdgcn_global_load_lds(
            (const __attribute__((address_space(1))) unsigned int*)(Bw + gb0 + koff),
            (__attribute__((address_space(3))) unsigned int*)&Bs[buf][i0 * 8], 16, 0, 0);
        __builtin_amdgcn_global_load_lds(
            (const __attribute__((address_space(1))) unsigned int*)(Bw + gb1 + koff),
            (__attribute__((address_space(3))) unsigned int*)&Bs[buf][i1 * 8], 16, 0, 0);
    };
    STAGE(0, kz0);
    STAGE(1, kz0 + 32);                       // nk >= 2 at all call sites
    asm volatile("s_waitcnt vmcnt(4)" ::: "memory");   // tile 0 landed
    __builtin_amdgcn_s_barrier();
    __builtin_amdgcn_sched_barrier(0);
    for (int kk = 0; kk < nk; kk++) {
        const int cur = kk % 3;
        if (kk + 2 < nk) STAGE((kk + 2) % 3, kz0 + (kk + 2) * 32);
        bf16x8 af[4], bq[4];
#pragma unroll
        for (int rb = 0; rb < 4; rb++)
            af[rb] = *reinterpret_cast<const bf16x8*>(
                &As[cur][(wr * 64 + rb * 16 + fr) * 32 + fq * 8]);
#pragma unroll
        for (int cb = 0; cb < 4; cb++)
            bq[cb] = *reinterpret_cast<const bf16x8*>(
                &Bs[cur][(wc * 64 + cb * 16 + fr) * 32 + fq * 8]);
#pragma unroll
        for (int rb = 0; rb < 4; rb++)
#pragma unroll
            for (int cb = 0; cb < 4; cb++)
                acc[rb][cb] = __builtin_amdgcn_mfma_f32_16x16x32_bf16(
                    af[rb], bq[cb], acc[rb][cb], 0, 0, 0);
        if (kk + 1 < nk) {
            if (kk + 2 < nk) {
                asm volatile("s_waitcnt vmcnt(4)" ::: "memory"); // tile k+1 in
            } else {
                asm volatile("s_waitcnt vmcnt(0)" ::: "memory"); // last tile in
            }
            __builtin_amdgcn_s_barrier();
            __builtin_amdgcn_sched_barrier(0);
        }
    }
#else
    for (int kk = 0; kk < nk; kk++) {
        const int koff = kz0 + kk * 32;
        const uint4 va0 = *reinterpret_cast<const uint4*>(A + ga0 + koff);
        const uint4 va1 = *reinterpret_cast<const uint4*>(A + ga1 + koff);
        const uint4 vb0 = *reinterpret_cast<const uint4*>(Bw + gb0 + koff);
        const uint4 vb1 = *reinterpret_cast<const uint4*>(Bw + gb1 + koff);
        __syncthreads();
        *reinterpret_cast<uint4*>(&As[0][i0 * 8]) = va0;
        *reinterpret_cast<uint4*>(&As[0][i1 * 8]) = va1;
        *reinterpret_cast<uint4*>(&Bs[0][i0 * 8]) = vb0;
        *reinterpret_cast<uint4*>(&Bs[0][i1 * 8]) = vb1;
        __syncthreads();
        bf16x8 af[4], bq[4];
#pragma unroll
        for (int rb = 0; rb < 4; rb++)
            af[rb] = *reinterpret_cast<const bf16x8*>(
                &As[0][(wr * 64 + rb * 16 + fr) * 32 + fq * 8]);
#pragma unroll
        for (int cb = 0; cb < 4; cb++)
            bq[cb] = *reinterpret_cast<const bf16x8*>(
                &Bs[0][(wc * 64 + cb * 16 + fr) * 32 + fq * 8]);
#pragma unroll
        for (int rb = 0; rb < 4; rb++)
#pragma unroll
            for (int cb = 0; cb < 4; cb++)
                acc[rb][cb] = __builtin_amdgcn_mfma_f32_16x16x32_bf16(
                    af[rb], bq[cb], acc[rb][cb], 0, 0, 0);
    }
#endif

    // C/D layout: col = lane&15, row = (lane>>4)*4 + reg
    float* Cz = Cf;
    if (EPI == 0)
        Cz = Cf + (size_t)blockIdx.z * (size_t)(gridDim.y * 128) * ldc;
    const int r0 = row0 + wr * 64, c0 = col0 + wc * 64;
#pragma unroll
    for (int rb = 0; rb < 4; rb++)
#pragma unroll
        for (int cb = 0; cb < 4; cb++) {
            const int col = c0 + cb * 16 + fr;
#pragma unroll
            for (int j = 0; j < 4; j++) {
                const int row = r0 + rb * 16 + fq * 4 + j;
                float v = acc[rb][cb][j];
                if (EPI == 0) {
                    Cz[(size_t)row * ldc + col] = v;
                } else if (EPI == 1) {
                    v = 1.f / (1.f + __expf(-(v + bias[col])));
                    v *= mul[(size_t)row * ldmul + col];
                    Cb[(size_t)row * ldc + col] = __float2bfloat16(v);
                } else if (EPI == 2) {
                    if (col0 < 2048) Cb[(size_t)row * 2048 + col] = __float2bfloat16(v);
                    else             Cb2[(size_t)row * 2048 + col - 2048] = __float2bfloat16(v);
                } else {
                    v += bias[col];
                    v = (v > 20.f) ? v : log1pf(__expf(v));
                    Cf[(size_t)row * ldc + col] = v;
                }
            }
        }
}

// Split-K reduce for x_dbl (128-wide padded, 8 slices), emits bf16 dt_r.
__global__ __launch_bounds__(256) void reduce_xdbl(
    const float* __restrict__ part, float* __restrict__ xdbl,
    __hip_bfloat16* __restrict__ dtr)
{
    const int i = blockIdx.x * 256 + threadIdx.x;   // 4096*128
    float s = 0.f;
#pragma unroll
    for (int j = 0; j < 8; j++) s += part[(size_t)j * 524288 + i];
    xdbl[i] = s;
    const int col = i & 127;
    if (col < 64) dtr[((i >> 7) << 6) + col] = __float2bfloat16(s);
}

// Depthwise causal conv (width 4) + bias + SiLU. bf16 in -> bf16 out.
__global__ __launch_bounds__(256) void conv_silu_kernel(
    const __hip_bfloat16* __restrict__ xin_b, const float* __restrict__ cw,
    const float* __restrict__ cb, __hip_bfloat16* __restrict__ xcb)
{
    int gid = blockIdx.x * 256 + threadIdx.x;   // 4096 * 2048 threads
    int e = gid & (DINNER - 1);
    int row = gid >> 11;
    int t = row & (L_SEQ - 1);
    float s = cb[e];
#pragma unroll
    for (int j = 0; j < 4; j++) {
        int tt = t - 3 + j;
        if (tt >= 0)
            s = fmaf(cw[e * 4 + j],
                     __bfloat162float(xin_b[(size_t)(row - 3 + j) * 2048 + e]), s);
    }
    xcb[(size_t)row * 2048 + e] = __float2bfloat16(s / (1.f + __expf(-s)));
}

// ---------------------------------------------------------------------------
// Chunked selective scan, lane-owns-channel layout (unchanged from R9).
// hloc/Pp: (NCHUNK-1)*B*DINNER*DSTATE, h0: NCHUNK*B*DINNER*DSTATE floats.
// ---------------------------------------------------------------------------
__global__ __launch_bounds__(256) void scan_pass_a(
    const float* __restrict__ dtp, const __hip_bfloat16* __restrict__ xcb,
    const float* __restrict__ xdbl, const float* __restrict__ A_log,
    float* __restrict__ hloc, float* __restrict__ Pp)
{
    __shared__ float sB[LCH][16];
    const int tid = threadIdx.x;
    const int e = (blockIdx.x << 8) + tid;
    const int chunk = blockIdx.y;             // 0..NCHUNK-2
    const int b = blockIdx.z;
    const int t0 = chunk * LCH;

    {   // stage B tile: 64 rows x 16 s (256 float4 loads)
        const int r = tid >> 2, sl = tid & 3;
        *(float4*)&sB[r][sl * 4] =
            *(const float4*)&xdbl[(size_t)(b * L_SEQ + t0 + r) * 128 + 64 + sl * 4];
    }
    float av[16];
#pragma unroll
    for (int sq = 0; sq < 4; sq++) {
        const float4 al = *(const float4*)&A_log[e * 16 + sq * 4];
#pragma unroll
        for (int j = 0; j < 4; j++)
            av[sq * 4 + j] = -fast_exp2(((const float*)&al)[j] * LOG2E);
    }
    float h[16];
#pragma unroll
    for (int s = 0; s < 16; s++) h[s] = 0.f;
    float sdt = 0.f;
    __syncthreads();

    const size_t rb = (size_t)(b * L_SEQ + t0) * 2048 + e;
    float dtv_n = dtp[rb];
    float xv_n = __bfloat162float(xcb[rb]);
    for (int t = 0; t < LCH; t++) {
        const float dtv = dtv_n, xv = xv_n;
        if (t + 1 < LCH) {
            dtv_n = dtp[rb + (size_t)(t + 1) * 2048];
            xv_n = __bfloat162float(xcb[rb + (size_t)(t + 1) * 2048]);
        }
        sdt += dtv;
        const float dtx = dtv * xv;
        const float dl2 = dtv * LOG2E;
#pragma unroll
        for (int sq = 0; sq < 4; sq++) {
            const float4 B4 = *(const float4*)&sB[t][sq * 4];
#pragma unroll
            for (int j = 0; j < 4; j++) {
                const int s = sq * 4 + j;
                const float Bv = ((const float*)&B4)[j];
                h[s] = fmaf(fast_exp2(dl2 * av[s]), h[s], Bv * dtx);
            }
        }
    }
    const size_t o = (((size_t)chunk * BATCH + b) * 2048 + e) * 16;
#pragma unroll
    for (int sq = 0; sq < 4; sq++) {
        *(float4*)&hloc[o + sq * 4] =
            make_float4(h[sq * 4], h[sq * 4 + 1], h[sq * 4 + 2], h[sq * 4 + 3]);
        *(float4*)&Pp[o + sq * 4] = make_float4(
            fast_exp2(av[sq * 4] * sdt * LOG2E),
            fast_exp2(av[sq * 4 + 1] * sdt * LOG2E),
            fast_exp2(av[sq * 4 + 2] * sdt * LOG2E),
            fast_exp2(av[sq * 4 + 3] * sdt * LOG2E));
    }
}

__global__ __launch_bounds__(256) void scan_pass_b(
    const float* __restrict__ hloc, const float* __restrict__ Pp,
    float* __restrict__ h0)
{
    const int idx = blockIdx.x * 256 + threadIdx.x;   // 65536
    float h = 0.f;
    h0[idx] = 0.f;
    for (int c = 0; c < NCHUNK - 1; c++) {
        h = fmaf(Pp[(size_t)c * 65536 + idx], h, hloc[(size_t)c * 65536 + idx]);
        h0[(size_t)(c + 1) * 65536 + idx] = h;
    }
}

__global__ __launch_bounds__(256) void scan_pass_c(
    const float* __restrict__ dtp, const __hip_bfloat16* __restrict__ xcb,
    const float* __restrict__ xdbl, const __hip_bfloat16* __restrict__ zb,
    const float* __restrict__ A_log, const float* __restrict__ Dw,
    const float* __restrict__ h0, __hip_bfloat16* __restrict__ yb)
{
    __shared__ float sB[LCH][16];
    __shared__ float sC[LCH][16];
    const int tid = threadIdx.x;
    const int e = (blockIdx.x << 8) + tid;
    const int chunk = blockIdx.y;
    const int b = blockIdx.z;
    const int t0 = chunk * LCH;

    {
        const int r = tid >> 2, sl = tid & 3;
        const size_t base = (size_t)(b * L_SEQ + t0 + r) * 128;
        *(float4*)&sB[r][sl * 4] = *(const float4*)&xdbl[base + 64 + sl * 4];
        *(float4*)&sC[r][sl * 4] = *(const float4*)&xdbl[base + 80 + sl * 4];
    }
    float av[16];
#pragma unroll
    for (int sq = 0; sq < 4; sq++) {
        const float4 al = *(const float4*)&A_log[e * 16 + sq * 4];
#pragma unroll
        for (int j = 0; j < 4; j++)
            av[sq * 4 + j] = -fast_exp2(((const float*)&al)[j] * LOG2E);
    }
    const float De = Dw[e];
    float h[16];
    const size_t o = (((size_t)chunk * BATCH + b) * 2048 + e) * 16;
#pragma unroll
    for (int sq = 0; sq < 4; sq++) {
        const float4 hv = *(const float4*)&h0[o + sq * 4];
        h[sq * 4] = hv.x; h[sq * 4 + 1] = hv.y;
        h[sq * 4 + 2] = hv.z; h[sq * 4 + 3] = hv.w;
    }
    __syncthreads();

    const size_t rb = (size_t)(b * L_SEQ + t0) * 2048 + e;
    float dtv_n = dtp[rb];
    float xv_n = __bfloat162float(xcb[rb]);
    float zv_n = __bfloat162float(zb[rb]);
    for (int t = 0; t < LCH; t++) {
        const float dtv = dtv_n, xv = xv_n, zv = zv_n;
        if (t + 1 < LCH) {
            dtv_n = dtp[rb + (size_t)(t + 1) * 2048];
            xv_n = __bfloat162float(xcb[rb + (size_t)(t + 1) * 2048]);
            zv_n = __bfloat162float(zb[rb + (size_t)(t + 1) * 2048]);
        }
        const float dtx = dtv * xv;
        const float dl2 = dtv * LOG2E;
        float yp0 = 0.f, yp1 = 0.f, yp2 = 0.f, yp3 = 0.f;
#pragma unroll
        for (int sq = 0; sq < 4; sq++) {
            const float4 B4 = *(const float4*)&sB[t][sq * 4];
            const float4 C4 = *(const float4*)&sC[t][sq * 4];
#pragma unroll
            for (int j = 0; j < 4; j++) {
                const int s = sq * 4 + j;
                const float Bv = ((const float*)&B4)[j];
                const float Cv = ((const float*)&C4)[j];
                h[s] = fmaf(fast_exp2(dl2 * av[s]), h[s], Bv * dtx);
                if (sq == 0) yp0 = fmaf(h[s], Cv, yp0);
                else if (sq == 1) yp1 = fmaf(h[s], Cv, yp1);
                else if (sq == 2) yp2 = fmaf(h[s], Cv, yp2);
                else yp3 = fmaf(h[s], Cv, yp3);
            }
        }
        float yv = (yp0 + yp1) + (yp2 + yp3);
        yv = fmaf(De, xv, yv);
        const float sig = 1.f / (1.f + __expf(-zv));
        yb[rb + (size_t)t * 2048] = __float2bfloat16(yv * zv * sig);
    }
}

extern "C" void kernel_launch(void* const* d_in, const int* in_sizes, int n_in,
                              void* d_out, int out_size, void* d_ws, size_t ws_size,
                              hipStream_t stream)
{
    const float* x_f    = (const float*)d_in[0];
    const float* x_h    = (const float*)d_in[1];
    const float* W_hf   = (const float*)d_in[2];
    const float* b_hf   = (const float*)d_in[3];
    const float* W_in   = (const float*)d_in[4];
    const float* conv_w = (const float*)d_in[5];
    const float* conv_b = (const float*)d_in[6];
    const float* W_x    = (const float*)d_in[7];
    const float* W_dt   = (const float*)d_in[8];
    const float* b_dt   = (const float*)d_in[9];
    const float* A_log  = (const float*)d_in[10];
    const float* Dw     = (const float*)d_in[11];
    const float* W_out  = (const float*)d_in[12];
    float* out = (float*)d_out;
    float* ws  = (float*)d_ws;

    // Workspace (f32 units; same layout as R9). G4's split-K partials now
    // live in the dtp region (dead until G5 writes dtp AFTER reduce_xdbl
    // consumes the partials): part = 8 * 524288 = 4,194,304 f <= 8,388,608 f.
    __hip_bfloat16* wout_b = (__hip_bfloat16*)(ws);              // 1,048,576 f
    __hip_bfloat16* win_b  = (__hip_bfloat16*)(ws + 1048576);    // 2,097,152 f
    __hip_bfloat16* xh_b   = (__hip_bfloat16*)(ws + 3145728);    // 2,097,152 f
    __hip_bfloat16* whf_b  = (__hip_bfloat16*)(ws + 5242880);    //   524,288 f
    __hip_bfloat16* m_b    = (__hip_bfloat16*)(ws + 5767168);    // 2,097,152 f
    float*          hloc   = ws + 1048576;   // 2,097,152 f (scan overlay)
    float*          Pp     = ws + 3145728;   // 2,097,152 f (scan overlay)
    float*          h0     = ws + 5242880;   // 2,097,152 f (scan overlay)
    __hip_bfloat16* wx_b   = (__hip_bfloat16*)(ws + 7864320);    //   131,072 f
    __hip_bfloat16* wdt_b  = (__hip_bfloat16*)(ws + 7995392);    //    65,536 f
    __hip_bfloat16* dtr_b  = (__hip_bfloat16*)(ws + 8060928);    //   131,072 f
    float*          xdbl   = ws + 10289152;                      //   524,288 f
    __hip_bfloat16* xin_b  = (__hip_bfloat16*)(ws + 10813440);   // 4,194,304 f
    __hip_bfloat16* z_b    = (__hip_bfloat16*)(ws + 15007744);   // 4,194,304 f
    __hip_bfloat16* xc_b   = (__hip_bfloat16*)(ws + 19202048);   // 4,194,304 f
    float*          part   = ws + 23396352;  // 4,194,304 f (over dtp, dead then)
    float*          dtp    = ws + 23396352;                      // 8,388,608 f
    __hip_bfloat16* yb     = (__hip_bfloat16*)(ws + 31784960);   // 4,194,304 f

    // 0. pre-convert all static operands to bf16 (one fused launch)
    cvt_all<<<11648, 256, 0, stream>>>(
        W_out, W_in, x_h, W_hf, W_x, W_dt,
        wout_b, win_b, xh_b, whf_b, wx_b, wdt_b);

    // 1. m_b = bf16( x_f * sigmoid(x_h @ W_hf^T + b_hf) )
    mfma_gemm<1><<<dim3(8, 32, 1), 256, 0, stream>>>(
        xh_b, DMODEL, whf_b, DMODEL, DMODEL,
        nullptr, DMODEL, m_b, nullptr, b_hf, x_f, DMODEL);

    // 2. [x_in | z] = m @ W_in^T  (bf16 split planes)
    mfma_gemm<2><<<dim3(32, 32, 1), 256, 0, stream>>>(
        m_b, DMODEL, win_b, DMODEL, DMODEL,
        nullptr, 2048, xin_b, z_b, nullptr, nullptr, 0);

    // 3. xc_b = bf16( silu(causal_conv4(x_in) + conv_b) )
    conv_silu_kernel<<<32768, 256, 0, stream>>>(
        xin_b, conv_w, conv_b, xc_b);

    // 4. x_dbl = xc @ W_x^T (padded N=128, MFMA split-K 8) + reduce
    mfma_gemm<0><<<dim3(1, 32, 8), 256, 0, stream>>>(
        xc_b, DINNER, wx_b, DINNER, 256,
        part, 128, nullptr, nullptr, nullptr, nullptr, 0);
    reduce_xdbl<<<2048, 256, 0, stream>>>(part, xdbl, dtr_b);

    // 5. dt = softplus(dt_r @ W_dt^T + b_dt)   (overwrites the part region)
    mfma_gemm<3><<<dim3(16, 32, 1), 256, 0, stream>>>(
        dtr_b, 64, wdt_b, 64, 64,
        dtp, 2048, nullptr, nullptr, b_dt, nullptr, 0);

    // 6. chunked scan (lane-owns-channel)
    scan_pass_a<<<dim3(8, NCHUNK - 1, BATCH), 256, 0, stream>>>(
        dtp, xc_b, xdbl, A_log, hloc, Pp);
    scan_pass_b<<<256, 256, 0, stream>>>(hloc, Pp, h0);
    scan_pass_c<<<dim3(8, NCHUNK, BATCH), 256, 0, stream>>>(
        dtp, xc_b, xdbl, z_b, A_log, Dw, h0, yb);

    // 7. out = y @ W_out^T
    mfma_gemm<0><<<dim3(8, 32, 1), 256, 0, stream>>>(
        yb, DINNER, wout_b, DINNER, DINNER,
        out, DMODEL, nullptr, nullptr, nullptr, nullptr, 0);
}

// Round 11
// 304.217 us; speedup vs baseline: 8.5495x; 1.0311x over previous
//
#include <hip/hip_runtime.h>
#include <hip/hip_bf16.h>
#include <math.h>

#define L_SEQ  2048
#define BATCH  2
#define DMODEL 1024
#define DINNER 2048
#define DSTATE 16
#define NCHUNK 32
#define LCH    (L_SEQ / NCHUNK)  // 64

typedef __attribute__((ext_vector_type(8))) short bf16x8;
typedef __attribute__((ext_vector_type(4))) float f32x4;

__device__ __forceinline__ unsigned short f2bu(float x) {
    __hip_bfloat16 h = __float2bfloat16(x);
    return __builtin_bit_cast(unsigned short, h);
}
// v_exp_f32: D = 2^S0 (hardware exp2)
__device__ __forceinline__ float fast_exp2(float x) {
    float r; asm("v_exp_f32 %0, %1" : "=v"(r) : "v"(x)); return r;
}
#define LOG2E 1.44269504088896f

// ---------------------------------------------------------------------------
// Fused fp32 -> bf16 conversion for all static operands (one launch).
// Segments (vec4 blocks of 256 thr): Wout 2048 | Win 4096 | xh 4096 |
// Whf 1024 | Wx-pad 256 | Wdt 128  => grid 11648.
// ---------------------------------------------------------------------------
__global__ __launch_bounds__(256) void cvt_all(
    const float* __restrict__ Wout, const float* __restrict__ Win,
    const float* __restrict__ xh,   const float* __restrict__ Whf,
    const float* __restrict__ Wx,   const float* __restrict__ Wdt,
    __hip_bfloat16* __restrict__ dWout, __hip_bfloat16* __restrict__ dWin,
    __hip_bfloat16* __restrict__ dxh,   __hip_bfloat16* __restrict__ dWhf,
    __hip_bfloat16* __restrict__ dWx,   __hip_bfloat16* __restrict__ dWdt)
{
    int bid = blockIdx.x;
    const float* s; __hip_bfloat16* d;
    if (bid < 2048)       { s = Wout; d = dWout; }
    else if (bid < 6144)  { s = Win;  d = dWin;  bid -= 2048; }
    else if (bid < 10240) { s = xh;   d = dxh;   bid -= 6144; }
    else if (bid < 11264) { s = Whf;  d = dWhf;  bid -= 10240; }
    else if (bid < 11520) {
        // W_x (96x2048) -> 128x2048, rows 96..127 zero
        bid -= 11264;
        const int i = (bid * 256 + threadIdx.x) * 4;
        const int r = i >> 11;
        ushort4 u = {0, 0, 0, 0};
        if (r < 96) {
            const float4 v = *reinterpret_cast<const float4*>(&Wx[i]);
            u.x = f2bu(v.x); u.y = f2bu(v.y); u.z = f2bu(v.z); u.w = f2bu(v.w);
        }
        *reinterpret_cast<ushort4*>(&dWx[i]) = u;
        return;
    }
    else                  { s = Wdt;  d = dWdt;  bid -= 11520; }
    const int i = (bid * 256 + threadIdx.x) * 4;
    const float4 v = *reinterpret_cast<const float4*>(&s[i]);
    ushort4 u;
    u.x = f2bu(v.x); u.y = f2bu(v.y); u.z = f2bu(v.z); u.w = f2bu(v.w);
    *reinterpret_cast<ushort4*>(&d[i]) = u;
}

// ---------------------------------------------------------------------------
// MFMA bf16 GEMM: C[M,N] = epi(A[M,K] @ Bw[N,K]^T), 64x128 tile, BK=32,
// 4 waves (2x2), wave-tile 32x64 (2x4 fragments, 8 MFMA/K-step), 12 KB LDS.
// Small tile => many blocks/CU (G2: 2048 blocks = 8/CU) so block-level TLP
// hides staging latency (m102/m114 mechanism) -- R6/R9/R10 proved the
// 128^2 K-loop schedule is NOT the lever (all ~590 TF); parallelism is.
// Simple 2-barrier loop (race-free; compiler drains vmcnt at barrier).
// Split-K via gridDim.z (slice ksz, partial slice stride gridDim.y*64*ldc).
// EPI: 0 fp32 C; 1 bf16 C = sigmoid(acc+bias)*mul; 2 bf16 split planes
//      (col<2048 -> Cb, else Cb2, stride 2048); 3 bf16 softplus(acc+bias).
// ---------------------------------------------------------------------------
template <int EPI>
__global__ __launch_bounds__(256) void mfma_gemm(
    const __hip_bfloat16* __restrict__ A, int lda,
    const __hip_bfloat16* __restrict__ Bw, int ldb,
    int ksz,
    float* __restrict__ Cf, int ldc,
    __hip_bfloat16* __restrict__ Cb,
    __hip_bfloat16* __restrict__ Cb2,
    const float* __restrict__ bias,
    const float* __restrict__ mul, int ldmul)
{
    __shared__ unsigned short As[64 * 32];    // 4 KB
    __shared__ unsigned short Bs[128 * 32];   // 8 KB
    const int tid = threadIdx.x;
    const int row0 = blockIdx.y * 64;
    const int col0 = blockIdx.x * 128;
    const int wid = tid >> 6, lane = tid & 63;
    const int wr = wid >> 1, wc = wid & 1;
    const int fr = lane & 15, fq = lane >> 4;
    const int kz0 = blockIdx.z * ksz;

    f32x4 acc[2][4];
#pragma unroll
    for (int i = 0; i < 2; i++)
#pragma unroll
        for (int j = 0; j < 4; j++) acc[i][j] = (f32x4){0.f, 0.f, 0.f, 0.f};

    // staging: thread t covers A row t>>2 slot t&3 (256 items),
    // B rows t>>2 and 64+(t>>2), slot t&3 (512 items). 16B each.
    const size_t ga  = (size_t)(row0 + (tid >> 2)) * lda + (tid & 3) * 8;
    const size_t gb0 = (size_t)(col0 + (tid >> 2)) * ldb + (tid & 3) * 8;
    const size_t gb1 = (size_t)(col0 + 64 + (tid >> 2)) * ldb + (tid & 3) * 8;
    const int nk = ksz >> 5;

    for (int kk = 0; kk < nk; kk++) {
        const int koff = kz0 + kk * 32;
#if __has_builtin(__builtin_amdgcn_global_load_lds)
        __syncthreads();   // readers of previous tile done
        __builtin_amdgcn_global_load_lds(
            (const __attribute__((address_space(1))) unsigned int*)(A + ga + koff),
            (__attribute__((address_space(3))) unsigned int*)&As[tid * 8], 16, 0, 0);
        __builtin_amdgcn_global_load_lds(
            (const __attribute__((address_space(1))) unsigned int*)(Bw + gb0 + koff),
            (__attribute__((address_space(3))) unsigned int*)&Bs[tid * 8], 16, 0, 0);
        __builtin_amdgcn_global_load_lds(
            (const __attribute__((address_space(1))) unsigned int*)(Bw + gb1 + koff),
            (__attribute__((address_space(3))) unsigned int*)&Bs[2048 + tid * 8], 16, 0, 0);
        __syncthreads();   // staged tile visible (vmcnt drained by barrier)
#else
        const uint4 va  = *reinterpret_cast<const uint4*>(A + ga + koff);
        const uint4 vb0 = *reinterpret_cast<const uint4*>(Bw + gb0 + koff);
        const uint4 vb1 = *reinterpret_cast<const uint4*>(Bw + gb1 + koff);
        __syncthreads();
        *reinterpret_cast<uint4*>(&As[tid * 8]) = va;
        *reinterpret_cast<uint4*>(&Bs[tid * 8]) = vb0;
        *reinterpret_cast<uint4*>(&Bs[2048 + tid * 8]) = vb1;
        __syncthreads();
#endif
        bf16x8 af[2], bq[4];
#pragma unroll
        for (int rb = 0; rb < 2; rb++)
            af[rb] = *reinterpret_cast<const bf16x8*>(
                &As[(wr * 32 + rb * 16 + fr) * 32 + fq * 8]);
#pragma unroll
        for (int cb = 0; cb < 4; cb++)
            bq[cb] = *reinterpret_cast<const bf16x8*>(
                &Bs[(wc * 64 + cb * 16 + fr) * 32 + fq * 8]);
#pragma unroll
        for (int rb = 0; rb < 2; rb++)
#pragma unroll
            for (int cb = 0; cb < 4; cb++)
                acc[rb][cb] = __builtin_amdgcn_mfma_f32_16x16x32_bf16(
                    af[rb], bq[cb], acc[rb][cb], 0, 0, 0);
    }

    // C/D layout: col = lane&15, row = (lane>>4)*4 + reg
    float* Cz = Cf;
    if (EPI == 0)
        Cz = Cf + (size_t)blockIdx.z * (size_t)(gridDim.y * 64) * ldc;
    const int r0 = row0 + wr * 32, c0 = col0 + wc * 64;
#pragma unroll
    for (int rb = 0; rb < 2; rb++)
#pragma unroll
        for (int cb = 0; cb < 4; cb++) {
            const int col = c0 + cb * 16 + fr;
#pragma unroll
            for (int j = 0; j < 4; j++) {
                const int row = r0 + rb * 16 + fq * 4 + j;
                float v = acc[rb][cb][j];
                if (EPI == 0) {
                    Cz[(size_t)row * ldc + col] = v;
                } else if (EPI == 1) {
                    v = 1.f / (1.f + __expf(-(v + bias[col])));
                    v *= mul[(size_t)row * ldmul + col];
                    Cb[(size_t)row * ldc + col] = __float2bfloat16(v);
                } else if (EPI == 2) {
                    if (col0 < 2048) Cb[(size_t)row * 2048 + col] = __float2bfloat16(v);
                    else             Cb2[(size_t)row * 2048 + col - 2048] = __float2bfloat16(v);
                } else {
                    v += bias[col];
                    v = (v > 20.f) ? v : log1pf(__expf(v));
                    Cb[(size_t)row * ldc + col] = __float2bfloat16(v);
                }
            }
        }
}

// Split-K reduce for x_dbl (128-wide padded, 8 slices), emits bf16 dt_r.
__global__ __launch_bounds__(256) void reduce_xdbl(
    const float* __restrict__ part, float* __restrict__ xdbl,
    __hip_bfloat16* __restrict__ dtr)
{
    const int i = blockIdx.x * 256 + threadIdx.x;   // 4096*128
    float s = 0.f;
#pragma unroll
    for (int j = 0; j < 8; j++) s += part[(size_t)j * 524288 + i];
    xdbl[i] = s;
    const int col = i & 127;
    if (col < 64) dtr[((i >> 7) << 6) + col] = __float2bfloat16(s);
}

// Depthwise causal conv (width 4) + bias + SiLU. bf16 in -> bf16 out.
__global__ __launch_bounds__(256) void conv_silu_kernel(
    const __hip_bfloat16* __restrict__ xin_b, const float* __restrict__ cw,
    const float* __restrict__ cb, __hip_bfloat16* __restrict__ xcb)
{
    int gid = blockIdx.x * 256 + threadIdx.x;   // 4096 * 2048 threads
    int e = gid & (DINNER - 1);
    int row = gid >> 11;
    int t = row & (L_SEQ - 1);
    float s = cb[e];
#pragma unroll
    for (int j = 0; j < 4; j++) {
        int tt = t - 3 + j;
        if (tt >= 0)
            s = fmaf(cw[e * 4 + j],
                     __bfloat162float(xin_b[(size_t)(row - 3 + j) * 2048 + e]), s);
    }
    xcb[(size_t)row * 2048 + e] = __float2bfloat16(s / (1.f + __expf(-s)));
}

// ---------------------------------------------------------------------------
// Chunked selective scan, lane-owns-channel layout (dt now bf16).
// hloc/Pp: (NCHUNK-1)*B*DINNER*DSTATE, h0: NCHUNK*B*DINNER*DSTATE floats.
// ---------------------------------------------------------------------------
__global__ __launch_bounds__(256) void scan_pass_a(
    const __hip_bfloat16* __restrict__ dtb, const __hip_bfloat16* __restrict__ xcb,
    const float* __restrict__ xdbl, const float* __restrict__ A_log,
    float* __restrict__ hloc, float* __restrict__ Pp)
{
    __shared__ float sB[LCH][16];
    const int tid = threadIdx.x;
    const int e = (blockIdx.x << 8) + tid;
    const int chunk = blockIdx.y;             // 0..NCHUNK-2
    const int b = blockIdx.z;
    const int t0 = chunk * LCH;

    {   // stage B tile: 64 rows x 16 s (256 float4 loads)
        const int r = tid >> 2, sl = tid & 3;
        *(float4*)&sB[r][sl * 4] =
            *(const float4*)&xdbl[(size_t)(b * L_SEQ + t0 + r) * 128 + 64 + sl * 4];
    }
    float av[16];
#pragma unroll
    for (int sq = 0; sq < 4; sq++) {
        const float4 al = *(const float4*)&A_log[e * 16 + sq * 4];
#pragma unroll
        for (int j = 0; j < 4; j++)
            av[sq * 4 + j] = -fast_exp2(((const float*)&al)[j] * LOG2E);
    }
    float h[16];
#pragma unroll
    for (int s = 0; s < 16; s++) h[s] = 0.f;
    float sdt = 0.f;
    __syncthreads();

    const size_t rb = (size_t)(b * L_SEQ + t0) * 2048 + e;
    float dtv_n = __bfloat162float(dtb[rb]);
    float xv_n = __bfloat162float(xcb[rb]);
    for (int t = 0; t < LCH; t++) {
        const float dtv = dtv_n, xv = xv_n;
        if (t + 1 < LCH) {
            dtv_n = __bfloat162float(dtb[rb + (size_t)(t + 1) * 2048]);
            xv_n = __bfloat162float(xcb[rb + (size_t)(t + 1) * 2048]);
        }
        sdt += dtv;
        const float dtx = dtv * xv;
        const float dl2 = dtv * LOG2E;
#pragma unroll
        for (int sq = 0; sq < 4; sq++) {
            const float4 B4 = *(const float4*)&sB[t][sq * 4];
#pragma unroll
            for (int j = 0; j < 4; j++) {
                const int s = sq * 4 + j;
                const float Bv = ((const float*)&B4)[j];
                h[s] = fmaf(fast_exp2(dl2 * av[s]), h[s], Bv * dtx);
            }
        }
    }
    const size_t o = (((size_t)chunk * BATCH + b) * 2048 + e) * 16;
#pragma unroll
    for (int sq = 0; sq < 4; sq++) {
        *(float4*)&hloc[o + sq * 4] =
            make_float4(h[sq * 4], h[sq * 4 + 1], h[sq * 4 + 2], h[sq * 4 + 3]);
        *(float4*)&Pp[o + sq * 4] = make_float4(
            fast_exp2(av[sq * 4] * sdt * LOG2E),
            fast_exp2(av[sq * 4 + 1] * sdt * LOG2E),
            fast_exp2(av[sq * 4 + 2] * sdt * LOG2E),
            fast_exp2(av[sq * 4 + 3] * sdt * LOG2E));
    }
}

__global__ __launch_bounds__(256) void scan_pass_b(
    const float* __restrict__ hloc, const float* __restrict__ Pp,
    float* __restrict__ h0)
{
    const int idx = blockIdx.x * 256 + threadIdx.x;   // 65536
    float h = 0.f;
    h0[idx] = 0.f;
    for (int c = 0; c < NCHUNK - 1; c++) {
        h = fmaf(Pp[(size_t)c * 65536 + idx], h, hloc[(size_t)c * 65536 + idx]);
        h0[(size_t)(c + 1) * 65536 + idx] = h;
    }
}

__global__ __launch_bounds__(256) void scan_pass_c(
    const __hip_bfloat16* __restrict__ dtb, const __hip_bfloat16* __restrict__ xcb,
    const float* __restrict__ xdbl, const __hip_bfloat16* __restrict__ zb,
    const float* __restrict__ A_log, const float* __restrict__ Dw,
    const float* __restrict__ h0, __hip_bfloat16* __restrict__ yb)
{
    __shared__ float sB[LCH][16];
    __shared__ float sC[LCH][16];
    const int tid = threadIdx.x;
    const int e = (blockIdx.x << 8) + tid;
    const int chunk = blockIdx.y;
    const int b = blockIdx.z;
    const int t0 = chunk * LCH;

    {
        const int r = tid >> 2, sl = tid & 3;
        const size_t base = (size_t)(b * L_SEQ + t0 + r) * 128;
        *(float4*)&sB[r][sl * 4] = *(const float4*)&xdbl[base + 64 + sl * 4];
        *(float4*)&sC[r][sl * 4] = *(const float4*)&xdbl[base + 80 + sl * 4];
    }
    float av[16];
#pragma unroll
    for (int sq = 0; sq < 4; sq++) {
        const float4 al = *(const float4*)&A_log[e * 16 + sq * 4];
#pragma unroll
        for (int j = 0; j < 4; j++)
            av[sq * 4 + j] = -fast_exp2(((const float*)&al)[j] * LOG2E);
    }
    const float De = Dw[e];
    float h[16];
    const size_t o = (((size_t)chunk * BATCH + b) * 2048 + e) * 16;
#pragma unroll
    for (int sq = 0; sq < 4; sq++) {
        const float4 hv = *(const float4*)&h0[o + sq * 4];
        h[sq * 4] = hv.x; h[sq * 4 + 1] = hv.y;
        h[sq * 4 + 2] = hv.z; h[sq * 4 + 3] = hv.w;
    }
    __syncthreads();

    const size_t rb = (size_t)(b * L_SEQ + t0) * 2048 + e;
    float dtv_n = __bfloat162float(dtb[rb]);
    float xv_n = __bfloat162float(xcb[rb]);
    float zv_n = __bfloat162float(zb[rb]);
    for (int t = 0; t < LCH; t++) {
        const float dtv = dtv_n, xv = xv_n, zv = zv_n;
        if (t + 1 < LCH) {
            dtv_n = __bfloat162float(dtb[rb + (size_t)(t + 1) * 2048]);
            xv_n = __bfloat162float(xcb[rb + (size_t)(t + 1) * 2048]);
            zv_n = __bfloat162float(zb[rb + (size_t)(t + 1) * 2048]);
        }
        const float dtx = dtv * xv;
        const float dl2 = dtv * LOG2E;
        float yp0 = 0.f, yp1 = 0.f, yp2 = 0.f, yp3 = 0.f;
#pragma unroll
        for (int sq = 0; sq < 4; sq++) {
            const float4 B4 = *(const float4*)&sB[t][sq * 4];
            const float4 C4 = *(const float4*)&sC[t][sq * 4];
#pragma unroll
            for (int j = 0; j < 4; j++) {
                const int s = sq * 4 + j;
                const float Bv = ((const float*)&B4)[j];
                const float Cv = ((const float*)&C4)[j];
                h[s] = fmaf(fast_exp2(dl2 * av[s]), h[s], Bv * dtx);
                if (sq == 0) yp0 = fmaf(h[s], Cv, yp0);
                else if (sq == 1) yp1 = fmaf(h[s], Cv, yp1);
                else if (sq == 2) yp2 = fmaf(h[s], Cv, yp2);
                else yp3 = fmaf(h[s], Cv, yp3);
            }
        }
        float yv = (yp0 + yp1) + (yp2 + yp3);
        yv = fmaf(De, xv, yv);
        const float sig = 1.f / (1.f + __expf(-zv));
        yb[rb + (size_t)t * 2048] = __float2bfloat16(yv * zv * sig);
    }
}

extern "C" void kernel_launch(void* const* d_in, const int* in_sizes, int n_in,
                              void* d_out, int out_size, void* d_ws, size_t ws_size,
                              hipStream_t stream)
{
    const float* x_f    = (const float*)d_in[0];
    const float* x_h    = (const float*)d_in[1];
    const float* W_hf   = (const float*)d_in[2];
    const float* b_hf   = (const float*)d_in[3];
    const float* W_in   = (const float*)d_in[4];
    const float* conv_w = (const float*)d_in[5];
    const float* conv_b = (const float*)d_in[6];
    const float* W_x    = (const float*)d_in[7];
    const float* W_dt   = (const float*)d_in[8];
    const float* b_dt   = (const float*)d_in[9];
    const float* A_log  = (const float*)d_in[10];
    const float* Dw     = (const float*)d_in[11];
    const float* W_out  = (const float*)d_in[12];
    float* out = (float*)d_out;
    float* ws  = (float*)d_ws;

    // Workspace (f32 units; total 35,979,264 f = 143.9 MB, proven-safe).
    // GEMM-phase bf16 buffers [1048576, 7864320) are dead after G2 and are
    // overlaid by scan-phase hloc/Pp/h0 (cvt re-writes them every call).
    // part (G4 partials, 4,194,304 f) is dead after reduce_xdbl; dt_b
    // occupies its own region (no overlay).
    __hip_bfloat16* wout_b = (__hip_bfloat16*)(ws);              // 1,048,576 f
    __hip_bfloat16* win_b  = (__hip_bfloat16*)(ws + 1048576);    // 2,097,152 f
    __hip_bfloat16* xh_b   = (__hip_bfloat16*)(ws + 3145728);    // 2,097,152 f
    __hip_bfloat16* whf_b  = (__hip_bfloat16*)(ws + 5242880);    //   524,288 f
    __hip_bfloat16* m_b    = (__hip_bfloat16*)(ws + 5767168);    // 2,097,152 f
    float*          hloc   = ws + 1048576;   // 2,097,152 f (scan overlay)
    float*          Pp     = ws + 3145728;   // 2,097,152 f (scan overlay)
    float*          h0     = ws + 5242880;   // 2,097,152 f (scan overlay)
    __hip_bfloat16* wx_b   = (__hip_bfloat16*)(ws + 7864320);    //   131,072 f
    __hip_bfloat16* wdt_b  = (__hip_bfloat16*)(ws + 7995392);    //    65,536 f
    __hip_bfloat16* dtr_b  = (__hip_bfloat16*)(ws + 8060928);    //   131,072 f
    float*          xdbl   = ws + 10289152;                      //   524,288 f
    __hip_bfloat16* xin_b  = (__hip_bfloat16*)(ws + 10813440);   // 4,194,304 f
    __hip_bfloat16* z_b    = (__hip_bfloat16*)(ws + 15007744);   // 4,194,304 f
    __hip_bfloat16* xc_b   = (__hip_bfloat16*)(ws + 19202048);   // 4,194,304 f
    float*          part   = ws + 23396352;                      // 4,194,304 f
    __hip_bfloat16* dt_b   = (__hip_bfloat16*)(ws + 27590656);   // 4,194,304 f
    __hip_bfloat16* yb     = (__hip_bfloat16*)(ws + 31784960);   // 4,194,304 f

    // 0. pre-convert all static operands to bf16 (one fused launch)
    cvt_all<<<11648, 256, 0, stream>>>(
        W_out, W_in, x_h, W_hf, W_x, W_dt,
        wout_b, win_b, xh_b, whf_b, wx_b, wdt_b);

    // 1. m_b = bf16( x_f * sigmoid(x_h @ W_hf^T + b_hf) )   512 blocks
    mfma_gemm<1><<<dim3(8, 64, 1), 256, 0, stream>>>(
        xh_b, DMODEL, whf_b, DMODEL, DMODEL,
        nullptr, DMODEL, m_b, nullptr, b_hf, x_f, DMODEL);

    // 2. [x_in | z] = m @ W_in^T  (bf16 split planes)        2048 blocks
    mfma_gemm<2><<<dim3(32, 64, 1), 256, 0, stream>>>(
        m_b, DMODEL, win_b, DMODEL, DMODEL,
        nullptr, 2048, xin_b, z_b, nullptr, nullptr, 0);

    // 3. xc_b = bf16( silu(causal_conv4(x_in) + conv_b) )
    conv_silu_kernel<<<32768, 256, 0, stream>>>(
        xin_b, conv_w, conv_b, xc_b);

    // 4. x_dbl = xc @ W_x^T (padded N=128, split-K 8) + reduce   512 blocks
    mfma_gemm<0><<<dim3(1, 64, 8), 256, 0, stream>>>(
        xc_b, DINNER, wx_b, DINNER, 256,
        part, 128, nullptr, nullptr, nullptr, nullptr, 0);
    reduce_xdbl<<<2048, 256, 0, stream>>>(part, xdbl, dtr_b);

    // 5. dt_b = bf16( softplus(dt_r @ W_dt^T + b_dt) )       1024 blocks
    mfma_gemm<3><<<dim3(16, 64, 1), 256, 0, stream>>>(
        dtr_b, 64, wdt_b, 64, 64,
        nullptr, 2048, dt_b, nullptr, b_dt, nullptr, 0);

    // 6. chunked scan (lane-owns-channel)
    scan_pass_a<<<dim3(8, NCHUNK - 1, BATCH), 256, 0, stream>>>(
        dt_b, xc_b, xdbl, A_log, hloc, Pp);
    scan_pass_b<<<256, 256, 0, stream>>>(hloc, Pp, h0);
    scan_pass_c<<<dim3(8, NCHUNK, BATCH), 256, 0, stream>>>(
        dt_b, xc_b, xdbl, z_b, A_log, Dw, h0, yb);

    // 7. out = y @ W_out^T                                    512 blocks
    mfma_gemm<0><<<dim3(8, 64, 1), 256, 0, stream>>>(
        yb, DINNER, wout_b, DINNER, DINNER,
        out, DMODEL, nullptr, nullptr, nullptr, nullptr, 0);
}